// Round 5
// baseline (5729.690 us; speedup 1.0000x reference)
//
#include <hip/hip_runtime.h>

#define BB 65536
#define LL 128
#define HH 20
#define HH2 2

__device__ __forceinline__ float fexp(float x) {
    return __builtin_amdgcn_exp2f(x * 1.4426950408889634f);   // e^x via 2^(x*log2e)
}
__device__ __forceinline__ float frcp(float x) { return __builtin_amdgcn_rcpf(x); }
__device__ __forceinline__ float sigf(float x) { return frcp(1.0f + fexp(-x)); }
__device__ __forceinline__ float tanh_(float x) { return 1.0f - 2.0f * frcp(fexp(2.0f * x) + 1.0f); }
__device__ __forceinline__ float lrelu(float x) { return fmaxf(x, 0.01f * x); }
__device__ __forceinline__ void fma4(float4& a, float s, const float4 w) {
    a.x = fmaf(s, w.x, a.x);
    a.y = fmaf(s, w.y, a.y);
    a.z = fmaf(s, w.z, a.z);
    a.w = fmaf(s, w.w, a.w);
}
// DPP quad-perm helpers (compile-time ctrl). rotN: lane i gets lane (i+N)&3 of its quad.
template <int CTRL>
__device__ __forceinline__ float dpp_qp(float x) {
    int i = __builtin_bit_cast(int, x);
    int r = __builtin_amdgcn_update_dpp(0, i, CTRL, 0xF, 0xF, true);
    return __builtin_bit_cast(float, r);
}
#define ROT1 0x39  // [1,2,3,0]
#define ROT2 0x4E  // [2,3,0,1]
#define ROT3 0x93  // [3,0,1,2]
#define SWAP 0xB1  // [1,0,3,2]

// FOUR threads per batch element (a quad), q = lane&3.
//   layer 1: lane q computes gate-groups j = q*5 .. q*5+4   (5 of 20)
//   layer 2: lane q computes gate row j2 = q&1 (rows duplicated across pair-of-pairs)
// h1/c1 exchange via 3 quad_perm rotations, kept in ROTATION-RELATIVE order
// hrel[r][jj] = h1 of lane (q+r)&3 — no cndmask reassembly. The lane-dependence
// moves into the LDS weight COLUMN offset colq[r] = ((q+r)&3)*5 (static-indexed
// 4-reg array). The 4 distinct addresses per ds_read sit 80B apart = disjoint
// bank quads -> near-broadcast speed.
//
// LDS packing (gate-major float4): sW1[j][k].{x,y,z,w} = gates i,f,g,o of row j.
//   k=0,1: Wih1 cols; k=2..21: Whh1 cols (global h order); k=22: bih1+bhh1
// sW2[j][k]: k=0..19 out1-h cols, 20..39 out1-c cols, 40,41 h2 cols, 42 bias.
__global__ __launch_bounds__(256, 2) void sampler_lstm(
    const float* __restrict__ mu, const float* __restrict__ log_var,
    const float* __restrict__ eps0, const float* __restrict__ eps,
    const float* __restrict__ Wih1, const float* __restrict__ Whh1,
    const float* __restrict__ bih1, const float* __restrict__ bhh1,
    const float* __restrict__ Wih2, const float* __restrict__ Whh2,
    const float* __restrict__ bih2, const float* __restrict__ bhh2,
    float* __restrict__ out)
{
    __shared__ float4 sW1[HH][23];
    __shared__ float4 sW2[HH2][43];

    const int tid = threadIdx.x;
    for (int idx = tid; idx < HH * 23; idx += 256) {
        int j = idx / 23, k = idx % 23;
        float4 v;
        float* vp = (float*)&v;
        #pragma unroll
        for (int g = 0; g < 4; ++g) {
            int row = g * HH + j;
            float val;
            if (k < 2)       val = Wih1[row * 2 + k];
            else if (k < 22) val = Whh1[row * HH + (k - 2)];
            else             val = bih1[row] + bhh1[row];
            vp[g] = val;
        }
        sW1[j][k] = v;
    }
    for (int idx = tid; idx < HH2 * 43; idx += 256) {
        int j = idx / 43, k = idx % 43;
        float4 v;
        float* vp = (float*)&v;
        #pragma unroll
        for (int g = 0; g < 4; ++g) {
            int row = g * HH2 + j;
            float val;
            if (k < 40)      val = Wih2[row * 40 + k];
            else if (k < 42) val = Whh2[row * 2 + (k - 40)];
            else             val = bih2[row] + bhh2[row];
            vp[g] = val;
        }
        sW2[j][k] = v;
    }
    __syncthreads();

    const int gtid = blockIdx.x * 256 + tid;
    const int b    = gtid >> 2;
    const int q    = gtid & 3;

    const float* murow = mu + (size_t)b * LL;
    float* out_mu = out + (size_t)b * LL;
    float* out_lv = out_mu + (size_t)BB * LL;
    float* out_sp = out_mu + 2ul * (size_t)BB * LL;

    const float4* __restrict__ w1own = &sW1[q * 5][0];   // own 5 gate-group rows
    const float4* __restrict__ w2own = &sW2[q & 1][0];   // own layer-2 gate row

    int colq[4];
    #pragma unroll
    for (int r = 0; r < 4; ++r) colq[r] = ((q + r) & 3) * 5;   // W column base per rotation

    float hrel[4][5];            // h1 in rotation-relative order
    float c1own[5];
    #pragma unroll
    for (int r = 0; r < 4; ++r)
        #pragma unroll
        for (int jj = 0; jj < 5; ++jj) hrel[r][jj] = 0.f;
    #pragma unroll
    for (int jj = 0; jj < 5; ++jj) c1own[jj] = 0.f;
    float h2a = 0.f, h2b = 0.f, c2own = 0.f;

    float x0 = eps0[b] * fexp(0.5f * log_var[(size_t)b * LL]) + murow[0];
    float x1 = 0.f;

    #pragma unroll 1
    for (int t = 0; t < LL; ++t) {
        float mu_t  = murow[t];
        float eps_t = eps[(size_t)t * BB + b];

        // ---- layer 1: own 5 gate-groups, h in rotation order ----
        float h1n[5];
        #pragma unroll
        for (int jg = 0; jg < 5; ++jg) {
            const float4* wrow = w1own + jg * 23;
            float4 a = wrow[22];                       // bias (i,f,g,o)
            fma4(a, x0, wrow[0]);
            fma4(a, x1, wrow[1]);
            #pragma unroll
            for (int r = 0; r < 4; ++r)
                #pragma unroll
                for (int jj = 0; jj < 5; ++jj)
                    fma4(a, hrel[r][jj], wrow[2 + colq[r] + jj]);
            float cn = sigf(a.y) * c1own[jg] + sigf(a.x) * tanh_(a.z);
            c1own[jg] = cn;
            h1n[jg] = sigf(a.w) * tanh_(cn);
        }

        // ---- exchange (dpp rotations) + fused layer-2 accumulation ----
        float4 a2 = w2own[42];                         // layer-2 bias
        #pragma unroll
        for (int jj = 0; jj < 5; ++jj) {               // r = 0 (own values)
            hrel[0][jj] = h1n[jj];
            fma4(a2, lrelu(h1n[jj]),   w2own[colq[0] + jj]);
            fma4(a2, lrelu(c1own[jj]), w2own[20 + colq[0] + jj]);
        }
        #pragma unroll
        for (int jj = 0; jj < 5; ++jj) {               // r = 1
            float hv = dpp_qp<ROT1>(h1n[jj]);
            float cv = dpp_qp<ROT1>(c1own[jj]);
            hrel[1][jj] = hv;
            fma4(a2, lrelu(hv), w2own[colq[1] + jj]);
            fma4(a2, lrelu(cv), w2own[20 + colq[1] + jj]);
        }
        #pragma unroll
        for (int jj = 0; jj < 5; ++jj) {               // r = 2
            float hv = dpp_qp<ROT2>(h1n[jj]);
            float cv = dpp_qp<ROT2>(c1own[jj]);
            hrel[2][jj] = hv;
            fma4(a2, lrelu(hv), w2own[colq[2] + jj]);
            fma4(a2, lrelu(cv), w2own[20 + colq[2] + jj]);
        }
        #pragma unroll
        for (int jj = 0; jj < 5; ++jj) {               // r = 3
            float hv = dpp_qp<ROT3>(h1n[jj]);
            float cv = dpp_qp<ROT3>(c1own[jj]);
            hrel[3][jj] = hv;
            fma4(a2, lrelu(hv), w2own[colq[3] + jj]);
            fma4(a2, lrelu(cv), w2own[20 + colq[3] + jj]);
        }
        fma4(a2, h2a, w2own[40]);
        fma4(a2, h2b, w2own[41]);

        // ---- layer 2 gates (own row, duplicated across the two pairs) ----
        float cn2 = sigf(a2.y) * c2own + sigf(a2.x) * tanh_(a2.z);
        c2own = cn2;
        float h2own = sigf(a2.w) * tanh_(cn2);
        float h2oth = dpp_qp<SWAP>(h2own);
        h2a = (q & 1) ? h2oth : h2own;
        h2b = (q & 1) ? h2own : h2oth;

        if (q == 0) {
            out_mu[t] = h2a;
            out_sp[t] = eps_t * fexp(0.5f * h2b) + h2a;
        } else if (q == 1) {
            out_lv[t] = h2b;
        }

        x0 = mu_t;
        x1 = (float)t;
    }
}

extern "C" void kernel_launch(void* const* d_in, const int* in_sizes, int n_in,
                              void* d_out, int out_size, void* d_ws, size_t ws_size,
                              hipStream_t stream) {
    sampler_lstm<<<dim3(BB * 4 / 256), dim3(256), 0, stream>>>(
        (const float*)d_in[0],  (const float*)d_in[1],  (const float*)d_in[2],
        (const float*)d_in[3],  (const float*)d_in[4],  (const float*)d_in[5],
        (const float*)d_in[6],  (const float*)d_in[7],  (const float*)d_in[8],
        (const float*)d_in[9],  (const float*)d_in[10], (const float*)d_in[11],
        (float*)d_out);
}

// Round 6
// 2373.413 us; speedup vs baseline: 2.4141x; 2.4141x over previous
//
#include <hip/hip_runtime.h>

#define BB 65536
#define LL 128
#define HH 20
#define HH2 2
#define LOG2E 1.4426950408889634f

__device__ __forceinline__ float fexp(float x) {           // e^x (unscaled path)
    return __builtin_amdgcn_exp2f(x * LOG2E);
}
__device__ __forceinline__ float frcp(float x) { return __builtin_amdgcn_rcpf(x); }
// Pre-scaled activations: argument a = y*log2e (weights staged pre-multiplied).
__device__ __forceinline__ float sig_s(float a) {          // sigmoid(y)
    return frcp(1.0f + __builtin_amdgcn_exp2f(-a));
}
__device__ __forceinline__ float tanh_s(float a) {         // tanh(y)
    return 1.0f - 2.0f * frcp(__builtin_amdgcn_exp2f(a + a) + 1.0f);
}
__device__ __forceinline__ float lrelu(float x) { return fmaxf(x, 0.01f * x); }
__device__ __forceinline__ void fma4(float4& a, float s, const float4 w) {
    a.x = fmaf(s, w.x, a.x);
    a.y = fmaf(s, w.y, a.y);
    a.z = fmaf(s, w.z, a.z);
    a.w = fmaf(s, w.w, a.w);
}
// swap adjacent lanes (0<->1, 2<->3, ...) via DPP quad_perm [1,0,3,2] — pure VALU
__device__ __forceinline__ float dpp_swap(float x) {
    int i = __builtin_bit_cast(int, x);
    int r = __builtin_amdgcn_update_dpp(0, i, 0xB1, 0xF, 0xF, true);
    return __builtin_bit_cast(float, r);
}

// Two threads per batch element (adjacent lanes), half = lane&1.
//   layer 1: thread computes global gate-groups j = half*10 .. half*10+9
//   layer 2: thread computes gate row j2 = half
// Layer-2 accumulation fused into the exchange loop (no o1 arrays).
// ALL gate weights/biases staged pre-multiplied by log2(e) so the
// activations use exp2 directly (sig_s / tanh_s above) — gate OUTPUTS
// (h, c) remain true values, so recurrence and outputs are unchanged.
//
// VGPR discipline (R1/R2/R4 lessons): cap at 128 via __launch_bounds__(256,2)
// — the irreducible live set (~55 regs: 30 state + scalars + one acc) is far
// below the cap, and the excess R2 showed (196) was rematerializable LDS-read
// pipelining temps, which the cap trims without spilling. Every array index
// is compile-time static (full unroll) — rule #20.
//
// LDS packing (gate-major float4): sW1[j][k].{x,y,z,w} = gates i,f,g,o:
//   k=0,1: Wih1 cols; k=2..21: Whh1 cols; k=22: bih1+bhh1    (x log2e)
// sW2[j][k]: k=0..19 out1-h cols, 20..39 out1-c, 40,41 h2, 42 bias (x log2e)
__global__ __launch_bounds__(256, 2) void sampler_lstm(
    const float* __restrict__ mu, const float* __restrict__ log_var,
    const float* __restrict__ eps0, const float* __restrict__ eps,
    const float* __restrict__ Wih1, const float* __restrict__ Whh1,
    const float* __restrict__ bih1, const float* __restrict__ bhh1,
    const float* __restrict__ Wih2, const float* __restrict__ Whh2,
    const float* __restrict__ bih2, const float* __restrict__ bhh2,
    float* __restrict__ out)
{
    __shared__ float4 sW1[HH][23];
    __shared__ float4 sW2[HH2][43];

    const int tid = threadIdx.x;
    for (int idx = tid; idx < HH * 23; idx += 256) {
        int j = idx / 23, k = idx % 23;
        float4 v;
        float* vp = (float*)&v;
        #pragma unroll
        for (int g = 0; g < 4; ++g) {
            int row = g * HH + j;
            float val;
            if (k < 2)       val = Wih1[row * 2 + k];
            else if (k < 22) val = Whh1[row * HH + (k - 2)];
            else             val = bih1[row] + bhh1[row];
            vp[g] = val * LOG2E;
        }
        sW1[j][k] = v;
    }
    for (int idx = tid; idx < HH2 * 43; idx += 256) {
        int j = idx / 43, k = idx % 43;
        float4 v;
        float* vp = (float*)&v;
        #pragma unroll
        for (int g = 0; g < 4; ++g) {
            int row = g * HH2 + j;
            float val;
            if (k < 40)      val = Wih2[row * 40 + k];
            else if (k < 42) val = Whh2[row * 2 + (k - 40)];
            else             val = bih2[row] + bhh2[row];
            vp[g] = val * LOG2E;
        }
        sW2[j][k] = v;
    }
    __syncthreads();

    const int gtid = blockIdx.x * 256 + tid;
    const int b    = gtid >> 1;
    const int half = gtid & 1;
    const bool hi  = (half != 0);

    const float* murow = mu + (size_t)b * LL;
    float* out_mu = out + (size_t)b * LL;
    float* out_lv = out_mu + (size_t)BB * LL;
    float* out_sp = out_mu + 2ul * (size_t)BB * LL;

    const float4* __restrict__ w1base = &sW1[half * 10][0];   // own 10 gate-group rows
    const float4* __restrict__ w2row  = &sW2[half][0];        // own layer-2 gate row

    float h1lo[10], h1hi[10], c1own[10];
    #pragma unroll
    for (int j = 0; j < 10; ++j) { h1lo[j] = 0.f; h1hi[j] = 0.f; c1own[j] = 0.f; }
    float h2a = 0.f, h2b = 0.f, c2own = 0.f;

    float x0 = eps0[b] * fexp(0.5f * log_var[(size_t)b * LL]) + murow[0];
    float x1 = 0.f;

    #pragma unroll 1
    for (int t = 0; t < LL; ++t) {
        float mu_t  = murow[t];
        float eps_t = eps[(size_t)t * BB + b];

        // ---- layer 1: own 10 gate-groups (fully unrolled, static indices) ----
        float h1n[10];
        #pragma unroll
        for (int jj = 0; jj < 10; ++jj) {
            const float4* wrow = w1base + (size_t)jj * 23;
            float4 a = wrow[22];
            fma4(a, x0, wrow[0]);
            fma4(a, x1, wrow[1]);
            #pragma unroll
            for (int k = 0; k < 10; ++k) fma4(a, h1lo[k], wrow[2 + k]);
            #pragma unroll
            for (int k = 0; k < 10; ++k) fma4(a, h1hi[k], wrow[12 + k]);
            float cn = sig_s(a.y) * c1own[jj] + sig_s(a.x) * tanh_s(a.z);
            c1own[jj] = cn;
            h1n[jj] = sig_s(a.w) * tanh_s(cn * LOG2E);
        }

        // ---- exchange + fused layer-2 accumulation ----
        float4 a2 = w2row[42];                         // layer-2 bias (pre-scaled)
        #pragma unroll
        for (int jj = 0; jj < 10; ++jj) {
            float ho = dpp_swap(h1n[jj]);
            float co = dpp_swap(c1own[jj]);
            float h_lo = hi ? ho        : h1n[jj];     // global j = jj
            float h_hi = hi ? h1n[jj]   : ho;          // global j = 10+jj
            float c_lo = hi ? co        : c1own[jj];
            float c_hi = hi ? c1own[jj] : co;
            h1lo[jj] = h_lo;
            h1hi[jj] = h_hi;
            fma4(a2, lrelu(h_lo), w2row[jj]);
            fma4(a2, lrelu(h_hi), w2row[10 + jj]);
            fma4(a2, lrelu(c_lo), w2row[20 + jj]);
            fma4(a2, lrelu(c_hi), w2row[30 + jj]);
        }
        fma4(a2, h2a, w2row[40]);
        fma4(a2, h2b, w2row[41]);

        // ---- layer 2 gates (own row) ----
        float cn = sig_s(a2.y) * c2own + sig_s(a2.x) * tanh_s(a2.z);
        c2own = cn;
        float h2own = sig_s(a2.w) * tanh_s(cn * LOG2E);
        float h2oth = dpp_swap(h2own);
        h2a = hi ? h2oth : h2own;
        h2b = hi ? h2own : h2oth;

        if (!hi) {
            out_mu[t] = h2a;
            out_sp[t] = eps_t * __builtin_amdgcn_exp2f(0.5f * LOG2E * h2b) + h2a;
        } else {
            out_lv[t] = h2b;
        }

        x0 = mu_t;
        x1 = (float)t;
    }
}

extern "C" void kernel_launch(void* const* d_in, const int* in_sizes, int n_in,
                              void* d_out, int out_size, void* d_ws, size_t ws_size,
                              hipStream_t stream) {
    sampler_lstm<<<dim3(BB * 2 / 256), dim3(256), 0, stream>>>(
        (const float*)d_in[0],  (const float*)d_in[1],  (const float*)d_in[2],
        (const float*)d_in[3],  (const float*)d_in[4],  (const float*)d_in[5],
        (const float*)d_in[6],  (const float*)d_in[7],  (const float*)d_in[8],
        (const float*)d_in[9],  (const float*)d_in[10], (const float*)d_in[11],
        (float*)d_out);
}

// Round 7
// 820.704 us; speedup vs baseline: 6.9814x; 2.8919x over previous
//
#include <hip/hip_runtime.h>

#define BB 65536
#define LL 128
#define HH 20
#define HH2 2
#define LOG2E 1.4426950408889634f

__device__ __forceinline__ float fexp(float x) {           // e^x
    return __builtin_amdgcn_exp2f(x * LOG2E);
}
__device__ __forceinline__ float frcp(float x) { return __builtin_amdgcn_rcpf(x); }
// Pre-scaled activations: argument a = y*log2e (weights staged pre-multiplied).
__device__ __forceinline__ float sig_s(float a) {          // sigmoid(y)
    return frcp(1.0f + __builtin_amdgcn_exp2f(-a));
}
__device__ __forceinline__ float tanh_s(float a) {         // tanh(y), a = y*log2e
    return 1.0f - 2.0f * frcp(__builtin_amdgcn_exp2f(a + a) + 1.0f);
}
__device__ __forceinline__ float lrelu(float x) { return fmaxf(x, 0.01f * x); }
__device__ __forceinline__ void fma4(float4& a, float s, const float4 w) {
    a.x = fmaf(s, w.x, a.x);
    a.y = fmaf(s, w.y, a.y);
    a.z = fmaf(s, w.z, a.z);
    a.w = fmaf(s, w.w, a.w);
}
__device__ __forceinline__ float dpp_swap(float x) {       // lanes 0<->1, 2<->3 ...
    int i = __builtin_bit_cast(int, x);
    int r = __builtin_amdgcn_update_dpp(0, i, 0xB1, 0xF, 0xF, true);
    return __builtin_bit_cast(float, r);
}
#define FENCE() __builtin_amdgcn_sched_barrier(0)

// Two threads per batch element (adjacent lanes), half = lane&1.
//   layer 1: thread computes global gate-groups j = half*10 .. half*10+9
//   layer 2: thread computes gate row j2 = half
//
// PARTNER-RELATIVE state: hOwn[10] = own h1 values, hPart[10] = partner's
// (via dpp_swap). The own/partner -> global-column mapping lives in four
// pointers computed once (pO/pP column bases), so there are NO cndmask
// selects and every array index is compile-time static (rule #20).
//
// VGPR discipline: NO launch-bounds cap (R1/R4/R5: caps on this structure
// always spill). Instead sched_barrier(0) fences every 5 k-iterations stop
// the scheduler from hoisting >~10 ds_read_b128 temps, keeping natural
// pressure ~100 VGPR <= 128 so the HW grants 2 waves/SIMD (the grid cap).
//
// LDS packing (gate-major float4): sW1[j][k].{x,y,z,w} = gates i,f,g,o,
// all values pre-multiplied by log2e (gate outputs h,c stay true values):
//   k=0,1: Wih1 cols; k=2..21: Whh1 cols (global h order); k=22: bih1+bhh1
// sW2[j][k]: k=0..19 out1-h cols, 20..39 out1-c, 40,41 h2, 42 bias.
__global__ __launch_bounds__(256) void sampler_lstm(
    const float* __restrict__ mu, const float* __restrict__ log_var,
    const float* __restrict__ eps0, const float* __restrict__ eps,
    const float* __restrict__ Wih1, const float* __restrict__ Whh1,
    const float* __restrict__ bih1, const float* __restrict__ bhh1,
    const float* __restrict__ Wih2, const float* __restrict__ Whh2,
    const float* __restrict__ bih2, const float* __restrict__ bhh2,
    float* __restrict__ out)
{
    __shared__ float4 sW1[HH][23];
    __shared__ float4 sW2[HH2][43];

    const int tid = threadIdx.x;
    for (int idx = tid; idx < HH * 23; idx += 256) {
        int j = idx / 23, k = idx % 23;
        float4 v;
        float* vp = (float*)&v;
        #pragma unroll
        for (int g = 0; g < 4; ++g) {
            int row = g * HH + j;
            float val;
            if (k < 2)       val = Wih1[row * 2 + k];
            else if (k < 22) val = Whh1[row * HH + (k - 2)];
            else             val = bih1[row] + bhh1[row];
            vp[g] = val * LOG2E;
        }
        sW1[j][k] = v;
    }
    for (int idx = tid; idx < HH2 * 43; idx += 256) {
        int j = idx / 43, k = idx % 43;
        float4 v;
        float* vp = (float*)&v;
        #pragma unroll
        for (int g = 0; g < 4; ++g) {
            int row = g * HH2 + j;
            float val;
            if (k < 40)      val = Wih2[row * 40 + k];
            else if (k < 42) val = Whh2[row * 2 + (k - 40)];
            else             val = bih2[row] + bhh2[row];
            vp[g] = val * LOG2E;
        }
        sW2[j][k] = v;
    }
    __syncthreads();

    const int gtid = blockIdx.x * 256 + tid;
    const int b    = gtid >> 1;
    const int half = gtid & 1;
    const bool hi  = (half != 0);

    const float* murow = mu + (size_t)b * LL;
    float* out_mu = out + (size_t)b * LL;
    float* out_lv = out_mu + (size_t)BB * LL;
    float* out_sp = out_mu + 2ul * (size_t)BB * LL;

    // Own rows / per-lane column bases (computed once; lane-dependence lives here)
    const float4* __restrict__ w1row0 = &sW1[half * 10][0];     // own 10 gate-group rows
    const int coO = 2 + half * 10;            // layer-1 col base for OWN h values
    const int coP = 2 + (1 - half) * 10;      // layer-1 col base for PARTNER h values
    const float4* __restrict__ w2r  = &sW2[half][0];            // own layer-2 gate row
    const float4* __restrict__ w2hO = w2r + half * 10;          // out1-h own cols
    const float4* __restrict__ w2hP = w2r + (1 - half) * 10;    // out1-h partner cols
    const float4* __restrict__ w2cO = w2r + 20 + half * 10;     // out1-c own cols
    const float4* __restrict__ w2cP = w2r + 20 + (1 - half) * 10;

    float hOwn[10], hPart[10], c1own[10];
    #pragma unroll
    for (int j = 0; j < 10; ++j) { hOwn[j] = 0.f; hPart[j] = 0.f; c1own[j] = 0.f; }
    float h2a = 0.f, h2b = 0.f, c2own = 0.f;

    float x0 = eps0[b] * fexp(0.5f * log_var[(size_t)b * LL]) + murow[0];
    float x1 = 0.f;

    #pragma unroll 1
    for (int t = 0; t < LL; ++t) {
        float mu_t  = murow[t];
        float eps_t = eps[(size_t)t * BB + b];

        // ---- layer 1: own 10 gate-groups (static indices, fenced chunks) ----
        float h1n[10];
        #pragma unroll
        for (int jj = 0; jj < 10; ++jj) {
            const float4* wrow = w1row0 + (size_t)jj * 23;
            const float4* pO = wrow + coO;
            const float4* pP = wrow + coP;
            float4 a = wrow[22];
            fma4(a, x0, wrow[0]);
            fma4(a, x1, wrow[1]);
            #pragma unroll
            for (int k = 0; k < 5; ++k) { fma4(a, hOwn[k], pO[k]); fma4(a, hPart[k], pP[k]); }
            FENCE();                       // limit in-flight ds_read temps
            #pragma unroll
            for (int k = 5; k < 10; ++k) { fma4(a, hOwn[k], pO[k]); fma4(a, hPart[k], pP[k]); }
            FENCE();
            float cn = sig_s(a.y) * c1own[jj] + sig_s(a.x) * tanh_s(a.z);
            c1own[jj] = cn;
            h1n[jj] = sig_s(a.w) * tanh_s(cn * LOG2E);
        }

        // ---- exchange (dpp) + fused layer-2 accumulation (no selects) ----
        float4 a2 = w2r[42];
        #pragma unroll
        for (int jj = 0; jj < 10; ++jj) {
            float hp = dpp_swap(h1n[jj]);
            float cp = dpp_swap(c1own[jj]);
            hOwn[jj]  = h1n[jj];
            hPart[jj] = hp;
            fma4(a2, lrelu(h1n[jj]),   w2hO[jj]);
            fma4(a2, lrelu(hp),        w2hP[jj]);
            fma4(a2, lrelu(c1own[jj]), w2cO[jj]);
            fma4(a2, lrelu(cp),        w2cP[jj]);
            if (jj == 4) FENCE();
        }
        FENCE();
        fma4(a2, h2a, w2r[40]);
        fma4(a2, h2b, w2r[41]);

        // ---- layer 2 gates (own row) ----
        float cn = sig_s(a2.y) * c2own + sig_s(a2.x) * tanh_s(a2.z);
        c2own = cn;
        float h2own = sig_s(a2.w) * tanh_s(cn * LOG2E);
        float h2oth = dpp_swap(h2own);
        h2a = hi ? h2oth : h2own;
        h2b = hi ? h2own : h2oth;

        if (!hi) {
            out_mu[t] = h2a;
            out_sp[t] = eps_t * __builtin_amdgcn_exp2f(0.5f * LOG2E * h2b) + h2a;
        } else {
            out_lv[t] = h2b;
        }

        x0 = mu_t;
        x1 = (float)t;
    }
}

extern "C" void kernel_launch(void* const* d_in, const int* in_sizes, int n_in,
                              void* d_out, int out_size, void* d_ws, size_t ws_size,
                              hipStream_t stream) {
    sampler_lstm<<<dim3(BB * 2 / 256), dim3(256), 0, stream>>>(
        (const float*)d_in[0],  (const float*)d_in[1],  (const float*)d_in[2],
        (const float*)d_in[3],  (const float*)d_in[4],  (const float*)d_in[5],
        (const float*)d_in[6],  (const float*)d_in[7],  (const float*)d_in[8],
        (const float*)d_in[9],  (const float*)d_in[10], (const float*)d_in[11],
        (float*)d_out);
}

// Round 8
// 452.379 us; speedup vs baseline: 12.6657x; 1.8142x over previous
//
#include <hip/hip_runtime.h>

#define BB 65536
#define LL 128
#define HH 20
#define LOG2E 1.4426950408889634f

typedef __attribute__((ext_vector_type(8))) short  bf16x8;
typedef __attribute__((ext_vector_type(4))) float  f32x4;
typedef __attribute__((ext_vector_type(4))) int    i32x4;

__device__ __forceinline__ float frcp(float x)  { return __builtin_amdgcn_rcpf(x); }
// pre-scaled activations: argument a = y*log2e (weights pre-multiplied by log2e)
__device__ __forceinline__ float sig_s(float a) { return frcp(1.f + __builtin_amdgcn_exp2f(-a)); }
__device__ __forceinline__ float tanh_s(float a){ return 1.f - 2.f * frcp(__builtin_amdgcn_exp2f(a + a) + 1.f); }
__device__ __forceinline__ float lrelu(float x) { return fmaxf(x, 0.01f * x); }
__device__ __forceinline__ unsigned cvt_pk(float lo, float hi) {
    unsigned r;
    asm("v_cvt_pk_bf16_f32 %0, %1, %2" : "=v"(r) : "v"(lo), "v"(hi));
    return r;
}
__device__ __forceinline__ bf16x8 pack8(const float v[8]) {
    i32x4 t = { (int)cvt_pk(v[0], v[1]), (int)cvt_pk(v[2], v[3]),
                (int)cvt_pk(v[4], v[5]), (int)cvt_pk(v[6], v[7]) };
    return __builtin_bit_cast(bf16x8, t);
}

// MFMA formulation. One wave = 16 batch elements. Lane: b16 = lane&15 (batch
// column), q = lane>>4 (k/row quad).
//
// Layer 1 per step: D[80,16] = W_ext[80,32] . hx[32,16] via 5x mfma 16x16x32:
//   gate rows interleaved G = 4j+g (g in {i,f,gg,o}); C/D layout (m89-verified:
//   col=lane&15, row=4*(lane>>4)+reg) makes acc[T] regs = (i,f,gg,o) of group
//   j = 4T+q for batch b16 -> gate combining is lane-local, c1 state c1s[5].
//   K-cols: 0..19 = Whh1 (orig h order), 20 = Wih1[:,0], 21 = Wih1[:,1],
//   22 = bih1+bhh1 (B row 22 == 1.0), 23..31 = 0. All weights * log2e.
//   A/B k-slot map s(q,e) = 4q + (e&3) + 16*(e>>2), identical for both
//   operands (any consistent bijection gives the same contraction).
// h_new -> next step's B-frag via wave-private LDS hx[32][17] (in-order per
// wave, no barriers). Rows 20,21 rewritten each step with (mu_t, t).
//
// Layer 2 (8 gate rows) in VALU: per-lane partials over own 5 j's from LDS
// sw2, butterfly __shfl_xor(16/32) reduce; h2/c2 replicated across q-lanes.
__global__ __launch_bounds__(256) void sampler_lstm(
    const float* __restrict__ mu, const float* __restrict__ log_var,
    const float* __restrict__ eps0, const float* __restrict__ eps,
    const float* __restrict__ Wih1, const float* __restrict__ Whh1,
    const float* __restrict__ bih1, const float* __restrict__ bhh1,
    const float* __restrict__ Wih2, const float* __restrict__ Whh2,
    const float* __restrict__ bih2, const float* __restrict__ bhh2,
    float* __restrict__ out)
{
    __shared__ __align__(16) float sw2[43][8];   // [col j][gate row r], * log2e
    __shared__ float hx[4][32][17];              // per-wave [k][b16], padded

    const int tid = threadIdx.x;
    for (int idx = tid; idx < 43 * 8; idx += 256) {
        int j = idx >> 3, r = idx & 7;
        float val;
        if (j < 40)      val = Wih2[r * 40 + j];
        else if (j < 42) val = Whh2[r * 2 + (j - 40)];
        else             val = bih2[r] + bhh2[r];
        sw2[j][r] = val * LOG2E;
    }
    __syncthreads();

    const int wave = tid >> 6;
    const int lane = tid & 63;
    const int b16  = lane & 15;
    const int q    = lane >> 4;
    const int gb   = (blockIdx.x * 4 + wave) * 16 + b16;   // global batch elem

    float (*hxw)[17] = hx[wave];
    const f32x4* s2 = (const f32x4*)&sw2[0][0];            // col j -> s2[2j], s2[2j+1]

    // ---- layer-1 weight A-frags (registers, once) ----
    bf16x8 afrag[5];
    #pragma unroll
    for (int T = 0; T < 5; ++T) {
        int G = 16 * T + b16;            // interleaved gate index
        int j = G >> 2, g = G & 3;
        int row = g * HH + j;            // original weight row
        float v[8];
        #pragma unroll
        for (int e = 0; e < 8; ++e) {
            int k = 4 * q + (e & 3) + 16 * (e >> 2);
            float val;
            if (k < 20)       val = Whh1[row * HH + k];
            else if (k == 20) val = Wih1[row * 2 + 0];
            else if (k == 21) val = Wih1[row * 2 + 1];
            else if (k == 22) val = bih1[row] + bhh1[row];
            else              val = 0.f;
            v[e] = val * LOG2E;
        }
        afrag[T] = pack8(v);
    }

    // ---- init hx (rows 8q..8q+7 of own column) ----
    const float* murow = mu + (size_t)gb * LL;
    float samp0 = eps0[gb] * __builtin_amdgcn_exp2f(0.5f * LOG2E * log_var[(size_t)gb * LL])
                + murow[0];
    #pragma unroll
    for (int d = 0; d < 8; ++d) {
        int k = 8 * q + d;
        hxw[k][b16] = (k == 20) ? samp0 : (k == 22) ? 1.f : 0.f;
    }

    float* out_mu_p = out + (size_t)gb * LL;
    float* out_lv_p = out_mu_p + (size_t)BB * LL;
    float* out_sp_p = out_mu_p + 2ul * (size_t)BB * LL;

    float c1s[5];
    #pragma unroll
    for (int T = 0; T < 5; ++T) c1s[T] = 0.f;
    float h2a = 0.f, h2b = 0.f, c2a = 0.f, c2b = 0.f;

    #pragma unroll 1
    for (int t = 0; t < LL; ++t) {
        float mu_t = murow[t];

        // ---- B-frag from hx ----
        float bv[8];
        #pragma unroll
        for (int e = 0; e < 8; ++e) {
            int k = 4 * q + (e & 3) + 16 * (e >> 2);
            bv[e] = hxw[k][b16];
        }
        bf16x8 bfrag = pack8(bv);

        // ---- layer-1 gates: 5 MFMAs ----
        f32x4 acc[5];
        #pragma unroll
        for (int T = 0; T < 5; ++T) {
            f32x4 z = {0.f, 0.f, 0.f, 0.f};
            acc[T] = __builtin_amdgcn_mfma_f32_16x16x32_bf16(afrag[T], bfrag, z, 0, 0, 0);
        }

        // ---- combine gates (lane-local), fused layer-2 partials ----
        float hn[5];
        f32x4 pA = {0.f, 0.f, 0.f, 0.f}, pB = {0.f, 0.f, 0.f, 0.f};
        #pragma unroll
        for (int T = 0; T < 5; ++T) {
            float gi = acc[T][0], gf = acc[T][1], gg = acc[T][2], go = acc[T][3];
            float c = sig_s(gf) * c1s[T] + sig_s(gi) * tanh_s(gg);
            c1s[T] = c;
            float h = sig_s(go) * tanh_s(c * LOG2E);
            hn[T] = h;
            int j = 4 * T + q;
            float lh = lrelu(h), lc = lrelu(c);
            pA += s2[2 * j] * lh;
            pB += s2[2 * j + 1] * lh;
            pA += s2[2 * (20 + j)] * lc;
            pB += s2[2 * (20 + j) + 1] * lc;
        }

        // write h_new + next x into hx (wave-private, in-order)
        #pragma unroll
        for (int T = 0; T < 5; ++T) hxw[4 * T + q][b16] = hn[T];
        if (q == 1) hxw[20][b16] = mu_t;
        if (q == 2) hxw[21][b16] = (float)t;

        // ---- layer 2: butterfly reduce + recurrent/bias + gates ----
        float g2[8];
        #pragma unroll
        for (int r = 0; r < 4; ++r) { g2[r] = pA[r]; g2[4 + r] = pB[r]; }
        #pragma unroll
        for (int r = 0; r < 8; ++r) {
            g2[r] += __shfl_xor(g2[r], 16);
            g2[r] += __shfl_xor(g2[r], 32);
        }
        f32x4 gA = {g2[0], g2[1], g2[2], g2[3]};
        f32x4 gB = {g2[4], g2[5], g2[6], g2[7]};
        gA += s2[80] * h2a;  gB += s2[81] * h2a;     // col 40 (Whh2 h2a)
        gA += s2[82] * h2b;  gB += s2[83] * h2b;     // col 41 (Whh2 h2b)
        gA += s2[84];        gB += s2[85];           // col 42 (bias)

        // rows: 0=i0 1=i1 2=f0 3=f1 | 4=g0 5=g1 6=o0 7=o1
        c2a = sig_s(gA[2]) * c2a + sig_s(gA[0]) * tanh_s(gB[0]);
        c2b = sig_s(gA[3]) * c2b + sig_s(gA[1]) * tanh_s(gB[1]);
        h2a = sig_s(gB[2]) * tanh_s(c2a * LOG2E);
        h2b = sig_s(gB[3]) * tanh_s(c2b * LOG2E);

        if (q == 0) {
            float eps_t = eps[(size_t)t * BB + gb];
            out_mu_p[t] = h2a;
            out_lv_p[t] = h2b;
            out_sp_p[t] = eps_t * __builtin_amdgcn_exp2f(0.5f * LOG2E * h2b) + h2a;
        }
    }
}

extern "C" void kernel_launch(void* const* d_in, const int* in_sizes, int n_in,
                              void* d_out, int out_size, void* d_ws, size_t ws_size,
                              hipStream_t stream) {
    sampler_lstm<<<dim3(BB / 64), dim3(256), 0, stream>>>(
        (const float*)d_in[0],  (const float*)d_in[1],  (const float*)d_in[2],
        (const float*)d_in[3],  (const float*)d_in[4],  (const float*)d_in[5],
        (const float*)d_in[6],  (const float*)d_in[7],  (const float*)d_in[8],
        (const float*)d_in[9],  (const float*)d_in[10], (const float*)d_in[11],
        (float*)d_out);
}

// Round 9
// 325.727 us; speedup vs baseline: 17.5904x; 1.3888x over previous
//
#include <hip/hip_runtime.h>

#define BB 65536
#define LL 128
#define HH 20
#define LOG2E 1.4426950408889634f

typedef __attribute__((ext_vector_type(8))) short  bf16x8;
typedef __attribute__((ext_vector_type(4))) float  f32x4;
typedef __attribute__((ext_vector_type(4))) int    i32x4;

__device__ __forceinline__ float frcp(float x)  { return __builtin_amdgcn_rcpf(x); }
// pre-scaled activations: argument a = y*log2e (weights pre-multiplied by log2e)
__device__ __forceinline__ float sig_s(float a) { return frcp(1.f + __builtin_amdgcn_exp2f(-a)); }
__device__ __forceinline__ float tanh_s(float a){ return 1.f - 2.f * frcp(__builtin_amdgcn_exp2f(a + a) + 1.f); }
__device__ __forceinline__ float lrelu(float x) { return fmaxf(x, 0.01f * x); }
__device__ __forceinline__ unsigned cvt_pk(float lo, float hi) {
    unsigned r;
    asm("v_cvt_pk_bf16_f32 %0, %1, %2" : "=v"(r) : "v"(lo), "v"(hi));
    return r;
}
__device__ __forceinline__ bf16x8 pack8(const float* v) {
    i32x4 t = { (int)cvt_pk(v[0], v[1]), (int)cvt_pk(v[2], v[3]),
                (int)cvt_pk(v[4], v[5]), (int)cvt_pk(v[6], v[7]) };
    return __builtin_bit_cast(bf16x8, t);
}

// Both LSTM layers on MFMA. One wave = 16 batch elements; b16 = lane&15
// (batch col), q = lane>>4. k-slot map s(q,e) = 4q + (e&3) + 16*(e>>2),
// used consistently for A and B of each 32-k frag (relabeling argument:
// any per-frag bijection gives the correct contraction — R7 verified).
//
// L1: D[80,16] = W1ext[80,32] . hx[32,16], 5x mfma 16x16x32, gate rows
//     interleaved G=4j+g so acc[T] = (i,f,g,o) of group j=4T+q (lane-local).
//     hx rows: 0..19 h1, 20 x0, 21 x1, 22 one, 23 zero (k>=23 clamped).
// L2: D[8,16] = W2ext[8,64] . u2[64,16], 2x mfma (k 0..31, 32..63).
//     u2 rows: 0..19 lrelu(h1), 20..39 lrelu(c1), 40 h2a, 41 h2b, 42 one,
//     43 zero (k>=43 clamped). Result rows 0..3 at q0 (i0,i1,f0,f1),
//     rows 4..7 at q1 (g0,g1,o0,o1) -> 4x shfl_xor(16); q0 owns h2/c2.
// Outputs staged in LDS ob[3][16][20] (q0 writes), dumped every 16 steps
// as 64B-contiguous dwordx4 per row -> no partial-sector write blowup.
// All LDS is wave-private (in-order within wave) -> zero barriers.
__global__ __launch_bounds__(256) void sampler_lstm(
    const float* __restrict__ mu, const float* __restrict__ log_var,
    const float* __restrict__ eps0, const float* __restrict__ eps,
    const float* __restrict__ Wih1, const float* __restrict__ Whh1,
    const float* __restrict__ bih1, const float* __restrict__ bhh1,
    const float* __restrict__ Wih2, const float* __restrict__ Whh2,
    const float* __restrict__ bih2, const float* __restrict__ bhh2,
    float* __restrict__ out)
{
    __shared__ float hx[4][24][17];      // per-wave [k][b16]
    __shared__ float u2[4][44][17];      // per-wave [k][b16]
    __shared__ float ob[4][3][16][20];   // per-wave [out][b16][t16] (pad 20)

    const int tid  = threadIdx.x;
    const int wave = tid >> 6;
    const int lane = tid & 63;
    const int b16  = lane & 15;
    const int q    = lane >> 4;
    const int gb0  = (blockIdx.x * 4 + wave) * 16;
    const int gb   = gb0 + b16;

    float (*hxw)[17]     = hx[wave];
    float (*u2w)[17]     = u2[wave];
    float (*obw)[16][20] = ob[wave];

    // ---- L1 weight A-frags (registers, once) ----
    bf16x8 a1[5];
    #pragma unroll
    for (int T = 0; T < 5; ++T) {
        int G = 16 * T + b16;            // interleaved gate index (m = b16)
        int j = G >> 2, g = G & 3;
        int row = g * HH + j;
        float v[8];
        #pragma unroll
        for (int e = 0; e < 8; ++e) {
            int k = 4 * q + (e & 3) + 16 * (e >> 2);
            float val;
            if (k < 20)       val = Whh1[row * HH + k];
            else if (k == 20) val = Wih1[row * 2 + 0];
            else if (k == 21) val = Wih1[row * 2 + 1];
            else if (k == 22) val = bih1[row] + bhh1[row];
            else              val = 0.f;
            v[e] = val * LOG2E;
        }
        a1[T] = pack8(v);
    }
    // ---- L2 weight A-frags (rows 0..7 natural order i0,i1,f0,f1,g0,g1,o0,o1) ----
    bf16x8 a2f[2];
    #pragma unroll
    for (int f = 0; f < 2; ++f) {
        float v[8];
        #pragma unroll
        for (int e = 0; e < 8; ++e) {
            int k = 32 * f + 4 * q + (e & 3) + 16 * (e >> 2);
            float val = 0.f;
            if (b16 < 8) {
                int r = b16;
                if (k < 40)       val = Wih2[r * 40 + k];
                else if (k == 40) val = Whh2[r * 2 + 0];
                else if (k == 41) val = Whh2[r * 2 + 1];
                else if (k == 42) val = bih2[r] + bhh2[r];
            }
            v[e] = val * LOG2E;
        }
        a2f[f] = pack8(v);
    }

    // ---- init state LDS ----
    const float* murow = mu + (size_t)gb * LL;
    float samp0 = eps0[gb] * __builtin_amdgcn_exp2f(0.5f * LOG2E * log_var[(size_t)gb * LL])
                + murow[0];
    #pragma unroll
    for (int d = 0; d < 6; ++d) {
        int r = 6 * q + d;
        hxw[r][b16] = (r == 20) ? samp0 : (r == 22) ? 1.f : 0.f;
    }
    #pragma unroll
    for (int d = 0; d < 11; ++d) {
        int r = 11 * q + d;
        u2w[r][b16] = (r == 42) ? 1.f : 0.f;
    }

    float c1s[5];
    #pragma unroll
    for (int T = 0; T < 5; ++T) c1s[T] = 0.f;
    float h2a = 0.f, h2b = 0.f, c2a = 0.f, c2b = 0.f;

    #pragma unroll 1
    for (int tb = 0; tb < 8; ++tb) {
        #pragma unroll 1
        for (int ti = 0; ti < 16; ++ti) {
            int t = tb * 16 + ti;
            float mu_t = murow[t];

            // ---- L1 B-frag (rows >=23 are zero; clamp to zero-row 23) ----
            float bv[8];
            #pragma unroll
            for (int e = 0; e < 8; ++e) {
                int k = 4 * q + (e & 3) + 16 * (e >> 2);
                if (k > 23) k = 23;
                bv[e] = hxw[k][b16];
            }
            bf16x8 b1 = pack8(bv);

            f32x4 acc[5];
            #pragma unroll
            for (int T = 0; T < 5; ++T) {
                f32x4 z = {0.f, 0.f, 0.f, 0.f};
                acc[T] = __builtin_amdgcn_mfma_f32_16x16x32_bf16(a1[T], b1, z, 0, 0, 0);
            }

            // ---- L1 gates (lane-local) + state writes ----
            float hn[5];
            #pragma unroll
            for (int T = 0; T < 5; ++T) {
                float c = sig_s(acc[T][1]) * c1s[T] + sig_s(acc[T][0]) * tanh_s(acc[T][2]);
                c1s[T] = c;
                hn[T] = sig_s(acc[T][3]) * tanh_s(c * LOG2E);
            }
            #pragma unroll
            for (int T = 0; T < 5; ++T) {
                hxw[4 * T + q][b16]      = hn[T];
                u2w[4 * T + q][b16]      = lrelu(hn[T]);
                u2w[20 + 4 * T + q][b16] = lrelu(c1s[T]);
            }
            if (q == 1) hxw[20][b16] = mu_t;
            if (q == 2) hxw[21][b16] = (float)t;

            // ---- L2 B-frags (rows >=43 zero; clamp) ----
            float cv[16];
            #pragma unroll
            for (int e = 0; e < 8; ++e) {
                int k = 4 * q + (e & 3) + 16 * (e >> 2);
                cv[e] = u2w[k][b16];
            }
            #pragma unroll
            for (int e = 0; e < 8; ++e) {
                int k = 32 + 4 * q + (e & 3) + 16 * (e >> 2);
                if (k > 43) k = 43;
                cv[8 + e] = u2w[k][b16];
            }
            bf16x8 b2a = pack8(cv);
            bf16x8 b2b = pack8(cv + 8);

            f32x4 z2 = {0.f, 0.f, 0.f, 0.f};
            f32x4 g2 = __builtin_amdgcn_mfma_f32_16x16x32_bf16(a2f[0], b2a, z2, 0, 0, 0);
            g2 = __builtin_amdgcn_mfma_f32_16x16x32_bf16(a2f[1], b2b, g2, 0, 0, 0);

            // q0 holds rows 0..3 (i0,i1,f0,f1); q1 holds rows 4..7 (g0,g1,o0,o1)
            float gg0 = __shfl_xor(g2[0], 16);
            float gg1 = __shfl_xor(g2[1], 16);
            float go0 = __shfl_xor(g2[2], 16);
            float go1 = __shfl_xor(g2[3], 16);
            c2a = sig_s(g2[2]) * c2a + sig_s(g2[0]) * tanh_s(gg0);
            c2b = sig_s(g2[3]) * c2b + sig_s(g2[1]) * tanh_s(gg1);
            h2a = sig_s(go0) * tanh_s(c2a * LOG2E);
            h2b = sig_s(go1) * tanh_s(c2b * LOG2E);

            if (q == 0) {
                u2w[40][b16] = h2a;
                u2w[41][b16] = h2b;
                float eps_t = eps[(size_t)t * BB + gb];
                obw[0][b16][ti] = h2a;
                obw[1][b16][ti] = h2b;
                obw[2][b16][ti] = eps_t * __builtin_amdgcn_exp2f(0.5f * LOG2E * h2b) + h2a;
            }
        }

        // ---- dump 16 timesteps, fully coalesced 64B per output row ----
        {
            int bq = lane >> 2, ch = lane & 3;
            #pragma unroll
            for (int o = 0; o < 3; ++o) {
                f32x4 v = *(const f32x4*)&obw[o][bq][ch * 4];
                float* dst = out + (size_t)o * BB * LL + (size_t)(gb0 + bq) * LL
                           + tb * 16 + ch * 4;
                *(float4*)dst = make_float4(v[0], v[1], v[2], v[3]);
            }
        }
    }
}

extern "C" void kernel_launch(void* const* d_in, const int* in_sizes, int n_in,
                              void* d_out, int out_size, void* d_ws, size_t ws_size,
                              hipStream_t stream) {
    sampler_lstm<<<dim3(BB / 64), dim3(256), 0, stream>>>(
        (const float*)d_in[0],  (const float*)d_in[1],  (const float*)d_in[2],
        (const float*)d_in[3],  (const float*)d_in[4],  (const float*)d_in[5],
        (const float*)d_in[6],  (const float*)d_in[7],  (const float*)d_in[8],
        (const float*)d_in[9],  (const float*)d_in[10], (const float*)d_in[11],
        (float*)d_out);
}

// Round 10
// 300.883 us; speedup vs baseline: 19.0429x; 1.0826x over previous
//
#include <hip/hip_runtime.h>

#define BB 65536
#define LL 128
#define HH 20
#define LOG2E 1.4426950408889634f

typedef __attribute__((ext_vector_type(8))) short  bf16x8;
typedef __attribute__((ext_vector_type(4))) float  f32x4;
typedef __attribute__((ext_vector_type(4))) int    i32x4;

__device__ __forceinline__ float frcp(float x)  { return __builtin_amdgcn_rcpf(x); }
// pre-scaled activations: argument a = y*log2e (weights pre-multiplied by log2e)
__device__ __forceinline__ float sig_s(float a) { return frcp(1.f + __builtin_amdgcn_exp2f(-a)); }
__device__ __forceinline__ float tanh_s(float a){ return 1.f - 2.f * frcp(__builtin_amdgcn_exp2f(a + a) + 1.f); }
__device__ __forceinline__ float lrelu(float x) { return fmaxf(x, 0.01f * x); }
__device__ __forceinline__ unsigned cvt_pk(float lo, float hi) {
    unsigned r;
    asm("v_cvt_pk_bf16_f32 %0, %1, %2" : "=v"(r) : "v"(lo), "v"(hi));
    return r;
}
__device__ __forceinline__ bf16x8 pack8v(f32x4 a, f32x4 b) {
    i32x4 t = { (int)cvt_pk(a[0], a[1]), (int)cvt_pk(a[2], a[3]),
                (int)cvt_pk(b[0], b[1]), (int)cvt_pk(b[2], b[3]) };
    return __builtin_bit_cast(bf16x8, t);
}

// Both layers MFMA; wave = 16 batch elems; b16 = lane&15, q = lane>>4.
// k-slot map s(q,e) = 4q+(e&3)+16(e>>2) used for A and B consistently.
//
// Merged TRANSPOSED state st[b16][52] (per wave):
//   cols 0..19 h1(raw) | 20 x0 | 21 x1 | 22 one | 23 zero |
//   24..43 c1(raw) | 44 h2a | 45 h2b | 46 one | 47 zero | 48..51 pad
// Zero A-columns kill don't-care B values => every B gather is a contiguous
// ds_read_b128 at col 4q / 16+4q / 32+4q. Stride 52 floats -> row starts at
// banks (20*b16)%32 = exact 2-way aliasing = free (m136).
//
// L1: A1[80,32] (gate rows interleaved G=16T+4q+p), cols: 0..19 Whh1,
//     20,21 Wih1, 22 bias, rest 0.  acc[T] = (i,f,g,o) of j=4T+q (lane-local).
// L2: A2[8,64] rows reordered m=4u+p (unit-major): rows 0..3 unit-a gates,
//     4..7 unit-b => q0 computes (c2a,h2a), q1 (c2b,h2b) IN PARALLEL (dedup).
//     A2 cols: 0..19 Wih2-h, 20..23 zero, 24..43 Wih2-c, 44,45 Whh2, 46 bias.
//     lrelu applied in-register at gather; the lrelu/raw boundary (43/44)
//     falls exactly on q3's b128, handled by one 4-wide cndmask group.
// Outputs staged in ob[3][16][20], dumped every 16 steps as coalesced b128.
// All LDS wave-private, zero barriers after init.
__global__ __launch_bounds__(256) void sampler_lstm(
    const float* __restrict__ mu, const float* __restrict__ log_var,
    const float* __restrict__ eps0, const float* __restrict__ eps,
    const float* __restrict__ Wih1, const float* __restrict__ Whh1,
    const float* __restrict__ bih1, const float* __restrict__ bhh1,
    const float* __restrict__ Wih2, const float* __restrict__ Whh2,
    const float* __restrict__ bih2, const float* __restrict__ bhh2,
    float* __restrict__ out)
{
    __shared__ __align__(16) float st[4][16][52];
    __shared__ __align__(16) float ob[4][3][16][20];

    const int tid  = threadIdx.x;
    const int wave = tid >> 6;
    const int lane = tid & 63;
    const int b16  = lane & 15;
    const int q    = lane >> 4;
    const int gb0  = (blockIdx.x * 4 + wave) * 16;
    const int gb   = gb0 + b16;

    float (*stw)[52]     = st[wave];
    float (*obw)[16][20] = ob[wave];

    // ---- L1 weight A-frags (registers, once) ----
    bf16x8 a1[5];
    #pragma unroll
    for (int T = 0; T < 5; ++T) {
        int G = 16 * T + b16;            // m index = b16
        int j = G >> 2, g = G & 3;
        int row = g * HH + j;
        float v[8];
        #pragma unroll
        for (int e = 0; e < 8; ++e) {
            int k = 4 * q + (e & 3) + 16 * (e >> 2);
            float val;
            if (k < 20)       val = Whh1[row * HH + k];
            else if (k == 20) val = Wih1[row * 2 + 0];
            else if (k == 21) val = Wih1[row * 2 + 1];
            else if (k == 22) val = bih1[row] + bhh1[row];
            else              val = 0.f;
            v[e] = val * LOG2E;
        }
        f32x4 lo = {v[0], v[1], v[2], v[3]}, hi4 = {v[4], v[5], v[6], v[7]};
        a1[T] = pack8v(lo, hi4);
    }
    // ---- L2 weight A-frags: rows m = 4u+p (unit-major), orig row = 2p+u ----
    bf16x8 a2f[2];
    #pragma unroll
    for (int f = 0; f < 2; ++f) {
        float v[8];
        #pragma unroll
        for (int e = 0; e < 8; ++e) {
            int k = 32 * f + 4 * q + (e & 3) + 16 * (e >> 2);
            float val = 0.f;
            if (b16 < 8) {
                int u = b16 >> 2, p = b16 & 3;
                int ro = 2 * p + u;
                if (k < 20)       val = Wih2[ro * 40 + k];
                else if (k < 24)  val = 0.f;
                else if (k < 44)  val = Wih2[ro * 40 + 20 + (k - 24)];
                else if (k == 44) val = Whh2[ro * 2 + 0];
                else if (k == 45) val = Whh2[ro * 2 + 1];
                else if (k == 46) val = bih2[ro] + bhh2[ro];
            }
            v[e] = val * LOG2E;
        }
        f32x4 lo = {v[0], v[1], v[2], v[3]}, hi4 = {v[4], v[5], v[6], v[7]};
        a2f[f] = pack8v(lo, hi4);
    }

    // ---- init state ----
    const float* murow = mu + (size_t)gb * LL;
    float samp0 = eps0[gb] * __builtin_amdgcn_exp2f(0.5f * LOG2E * log_var[(size_t)gb * LL])
                + murow[0];
    #pragma unroll
    for (int d = 0; d < 13; ++d) {
        int col = 13 * q + d;
        stw[b16][col] = (col == 20) ? samp0 : (col == 22 || col == 46) ? 1.f : 0.f;
    }

    float c1s[5];
    #pragma unroll
    for (int T = 0; T < 5; ++T) c1s[T] = 0.f;
    float c2 = 0.f, h2 = 0.f;

    #pragma unroll 1
    for (int tb = 0; tb < 8; ++tb) {
        #pragma unroll 1
        for (int ti = 0; ti < 16; ++ti) {
            int t = tb * 16 + ti;
            float mu_t = murow[t];

            // ---- L1 B-frag: 2x ds_read_b128 (old h / x-block / dont-care) ----
            f32x4 vA = *reinterpret_cast<const f32x4*>(&stw[b16][4 * q]);
            f32x4 vB = *reinterpret_cast<const f32x4*>(&stw[b16][16 + 4 * q]);
            bf16x8 b1 = pack8v(vA, vB);

            f32x4 acc[5];
            #pragma unroll
            for (int T = 0; T < 5; ++T) {
                f32x4 z = {0.f, 0.f, 0.f, 0.f};
                acc[T] = __builtin_amdgcn_mfma_f32_16x16x32_bf16(a1[T], b1, z, 0, 0, 0);
            }

            // ---- L1 gates (lane-local) + state writes ----
            float hn[5];
            #pragma unroll
            for (int T = 0; T < 5; ++T) {
                float c = sig_s(acc[T][1]) * c1s[T] + sig_s(acc[T][0]) * tanh_s(acc[T][2]);
                c1s[T] = c;
                hn[T] = sig_s(acc[T][3]) * tanh_s(c * LOG2E);
            }
            #pragma unroll
            for (int T = 0; T < 5; ++T) {
                stw[b16][4 * T + q]      = hn[T];      // new h
                stw[b16][24 + 4 * T + q] = c1s[T];     // new c (raw)
            }
            if (q == 1) { stw[b16][20] = mu_t; stw[b16][21] = (float)t; }

            // ---- L2 B-frags: 3x ds_read_b128, lrelu in-register ----
            f32x4 u0 = *reinterpret_cast<const f32x4*>(&stw[b16][4 * q]);       // new h
            f32x4 u1 = *reinterpret_cast<const f32x4*>(&stw[b16][16 + 4 * q]);  // h16..19 / x / c
            f32x4 u2 = *reinterpret_cast<const f32x4*>(&stw[b16][32 + 4 * q]);  // c / h2-block
            f32x4 l0, l1, l2;
            #pragma unroll
            for (int i = 0; i < 4; ++i) {
                l0[i] = lrelu(u0[i]);
                l1[i] = lrelu(u1[i]);
                l2[i] = (q < 3) ? lrelu(u2[i]) : u2[i];   // q3 reads h2a,h2b,one,zero raw
            }
            bf16x8 b2a = pack8v(l0, l1);
            bf16x8 b2b = pack8v(l2, l2);                  // k>=48: A zero, dup is fine

            f32x4 z2 = {0.f, 0.f, 0.f, 0.f};
            f32x4 g2 = __builtin_amdgcn_mfma_f32_16x16x32_bf16(a2f[0], b2a, z2, 0, 0, 0);
            g2 = __builtin_amdgcn_mfma_f32_16x16x32_bf16(a2f[1], b2b, g2, 0, 0, 0);

            // ---- L2 gates: q0 = unit a, q1 = unit b (parallel, no redundancy) ----
            c2 = sig_s(g2[1]) * c2 + sig_s(g2[0]) * tanh_s(g2[2]);
            h2 = sig_s(g2[3]) * tanh_s(c2 * LOG2E);

            if (q == 0) stw[b16][44] = h2;
            if (q == 1) stw[b16][45] = h2;
            float h2o = __shfl_xor(h2, 16);               // q0 <- q1's h2 (= h2b)

            if (q == 0) {
                float eps_t = eps[(size_t)t * BB + gb];
                obw[0][b16][ti] = h2;                                  // mu_r
                obw[1][b16][ti] = h2o;                                 // lv_r
                obw[2][b16][ti] = eps_t * __builtin_amdgcn_exp2f(0.5f * LOG2E * h2o) + h2;
            }
        }

        // ---- dump 16 timesteps, coalesced 64B rows ----
        {
            int bq = lane >> 2, ch = lane & 3;
            #pragma unroll
            for (int o = 0; o < 3; ++o) {
                f32x4 v = *reinterpret_cast<const f32x4*>(&obw[o][bq][ch * 4]);
                float* dst = out + (size_t)o * BB * LL + (size_t)(gb0 + bq) * LL
                           + tb * 16 + ch * 4;
                *(float4*)dst = make_float4(v[0], v[1], v[2], v[3]);
            }
        }
    }
}

extern "C" void kernel_launch(void* const* d_in, const int* in_sizes, int n_in,
                              void* d_out, int out_size, void* d_ws, size_t ws_size,
                              hipStream_t stream) {
    sampler_lstm<<<dim3(BB / 64), dim3(256), 0, stream>>>(
        (const float*)d_in[0],  (const float*)d_in[1],  (const float*)d_in[2],
        (const float*)d_in[3],  (const float*)d_in[4],  (const float*)d_in[5],
        (const float*)d_in[6],  (const float*)d_in[7],  (const float*)d_in[8],
        (const float*)d_in[9],  (const float*)d_in[10], (const float*)d_in[11],
        (float*)d_out);
}

// Round 11
// 269.986 us; speedup vs baseline: 21.2222x; 1.1144x over previous
//
#include <hip/hip_runtime.h>

#define BB 65536
#define LL 128
#define HH 20
#define LOG2E 1.4426950408889634f

typedef __attribute__((ext_vector_type(8))) short  bf16x8;
typedef __attribute__((ext_vector_type(4))) float  f32x4;
typedef __attribute__((ext_vector_type(4))) int    i32x4;

__device__ __forceinline__ float frcp(float x)  { return __builtin_amdgcn_rcpf(x); }
__device__ __forceinline__ float ex2(float x)   { return __builtin_amdgcn_exp2f(x); }
__device__ __forceinline__ float lrelu(float x) { return fmaxf(x, 0.01f * x); }
__device__ __forceinline__ float csign(float mag, float sgn) {   // v_bfi_b32
    int m = __builtin_bit_cast(int, mag), s = __builtin_bit_cast(int, sgn);
    return __builtin_bit_cast(float, (m & 0x7fffffff) | (s & 0x80000000));
}
__device__ __forceinline__ unsigned cvt_pk(float lo, float hi) {
    unsigned r;
    asm("v_cvt_pk_bf16_f32 %0, %1, %2" : "=v"(r) : "v"(lo), "v"(hi));
    return r;
}
__device__ __forceinline__ bf16x8 pack8v(f32x4 a, f32x4 b) {
    i32x4 t = { (int)cvt_pk(a[0], a[1]), (int)cvt_pk(a[2], a[3]),
                (int)cvt_pk(b[0], b[1]), (int)cvt_pk(b[2], b[3]) };
    return __builtin_bit_cast(bf16x8, t);
}

// Merged-rcp LSTM unit. a = (i,f,g,o) pre-activations ALREADY x log2e
// (weights staged pre-scaled); c,h are true values. Trans are the issue
// bottleneck (quarter-rate): this form uses 5 exp2 + 2 rcp vs the naive
// 5 exp2 + 5 rcp.  tanh via sign-safe e^{-2|x|} (in (0,1], never inf;
// sign reinserted with one v_bfi).
//   c' = sig(f)c + sig(i)tanh(g) = (c*B*deng + csign(numg*A, g)) / (A*B*deng)
//   h  = sig(o)tanh(c')          = csign(numc, c') / ((1+eo)(1+ecm))
__device__ __forceinline__ void lstm_unit(f32x4 a, float& c, float& h) {
    float ei  = ex2(-a[0]);
    float ef  = ex2(-a[1]);
    float eo  = ex2(-a[3]);
    float tg  = a[2] + a[2];
    float egm = ex2(-fabsf(tg));
    float numg = 1.f - egm, deng = 1.f + egm;
    float A = 1.f + ef, B = 1.f + ei;
    float P = B * deng;
    float D = P * A;
    float n2 = csign(numg * A, a[2]);
    float cn = fmaf(c, P, n2) * frcp(D);
    c = cn;
    float tc  = cn * (2.f * LOG2E);
    float ecm = ex2(-fabsf(tc));
    float numc = 1.f - ecm;
    float Do = (1.f + eo) * (1.f + ecm);
    h = csign(numc, cn) * frcp(Do);
}

// Both layers MFMA; wave = 16 batch elems; b16 = lane&15, q = lane>>4.
// k-slot map s(q,e) = 4q+(e&3)+16(e>>2), used consistently for A and B.
// Merged transposed state st[b16][52] (per wave):
//   0..19 h1 | 20 x0 | 21 x1 | 22 one | 23 zero | 24..43 c1 |
//   44 h2a | 45 h2b | 46 one | 47 zero | 48..51 pad
// Key unification: the L2 B gather (u0,u1 = cols 4q / 16+4q) is byte-
// identical to the NEXT step's L1 B-frag read -> read once, use raw for
// b1_next (pipelined across the loop) and lrelu'd for L2. 3 ds_read_b128
// per step total. Outputs staged in ob and dumped coalesced every 16 steps.
// All LDS wave-private, zero barriers after init.
__global__ __launch_bounds__(256) void sampler_lstm(
    const float* __restrict__ mu, const float* __restrict__ log_var,
    const float* __restrict__ eps0, const float* __restrict__ eps,
    const float* __restrict__ Wih1, const float* __restrict__ Whh1,
    const float* __restrict__ bih1, const float* __restrict__ bhh1,
    const float* __restrict__ Wih2, const float* __restrict__ Whh2,
    const float* __restrict__ bih2, const float* __restrict__ bhh2,
    float* __restrict__ out)
{
    __shared__ __align__(16) float st[4][16][52];
    __shared__ __align__(16) float ob[4][3][16][20];

    const int tid  = threadIdx.x;
    const int wave = tid >> 6;
    const int lane = tid & 63;
    const int b16  = lane & 15;
    const int q    = lane >> 4;
    const int gb0  = (blockIdx.x * 4 + wave) * 16;
    const int gb   = gb0 + b16;

    float (*stw)[52]     = st[wave];
    float (*obw)[16][20] = ob[wave];

    // ---- L1 weight A-frags (registers, once) ----
    bf16x8 a1[5];
    #pragma unroll
    for (int T = 0; T < 5; ++T) {
        int G = 16 * T + b16;
        int j = G >> 2, g = G & 3;
        int row = g * HH + j;
        float v[8];
        #pragma unroll
        for (int e = 0; e < 8; ++e) {
            int k = 4 * q + (e & 3) + 16 * (e >> 2);
            float val;
            if (k < 20)       val = Whh1[row * HH + k];
            else if (k == 20) val = Wih1[row * 2 + 0];
            else if (k == 21) val = Wih1[row * 2 + 1];
            else if (k == 22) val = bih1[row] + bhh1[row];
            else              val = 0.f;
            v[e] = val * LOG2E;
        }
        f32x4 lo = {v[0], v[1], v[2], v[3]}, hi4 = {v[4], v[5], v[6], v[7]};
        a1[T] = pack8v(lo, hi4);
    }
    // ---- L2 weight A-frags: rows m = 4u+p (unit-major), orig row = 2p+u ----
    bf16x8 a2f[2];
    #pragma unroll
    for (int f = 0; f < 2; ++f) {
        float v[8];
        #pragma unroll
        for (int e = 0; e < 8; ++e) {
            int k = 32 * f + 4 * q + (e & 3) + 16 * (e >> 2);
            float val = 0.f;
            if (b16 < 8) {
                int u = b16 >> 2, p = b16 & 3;
                int ro = 2 * p + u;
                if (k < 20)       val = Wih2[ro * 40 + k];
                else if (k < 24)  val = 0.f;
                else if (k < 44)  val = Wih2[ro * 40 + 20 + (k - 24)];
                else if (k == 44) val = Whh2[ro * 2 + 0];
                else if (k == 45) val = Whh2[ro * 2 + 1];
                else if (k == 46) val = bih2[ro] + bhh2[ro];
            }
            v[e] = val * LOG2E;
        }
        f32x4 lo = {v[0], v[1], v[2], v[3]}, hi4 = {v[4], v[5], v[6], v[7]};
        a2f[f] = pack8v(lo, hi4);
    }

    // ---- init state ----
    const float* murow = mu + (size_t)gb * LL;
    float samp0 = eps0[gb] * ex2(0.5f * LOG2E * log_var[(size_t)gb * LL]) + murow[0];
    #pragma unroll
    for (int d = 0; d < 13; ++d) {
        int col = 13 * q + d;
        stw[b16][col] = (col == 20) ? samp0 : (col == 22 || col == 46) ? 1.f : 0.f;
    }

    const f32x4 kz = {0.f, 0.f, 0.f, 0.f};
    float c1s[5];
    #pragma unroll
    for (int T = 0; T < 5; ++T) c1s[T] = 0.f;
    float c2 = 0.f;

    // prologue: L1 B-frag for t=0
    bf16x8 b1;
    {
        f32x4 v0 = *reinterpret_cast<const f32x4*>(&stw[b16][4 * q]);
        f32x4 v1 = *reinterpret_cast<const f32x4*>(&stw[b16][16 + 4 * q]);
        b1 = pack8v(v0, v1);
    }

    #pragma unroll 1
    for (int tb = 0; tb < 8; ++tb) {
        #pragma unroll 2
        for (int ti = 0; ti < 16; ++ti) {
            const int t = tb * 16 + ti;
            const float mu_t  = murow[t];
            const float eps_t = eps[(size_t)t * BB + gb];   // issued early, used late

            // ---- L1: 5 MFMAs (C = loop-invariant zero reg) ----
            f32x4 acc[5];
            #pragma unroll
            for (int T = 0; T < 5; ++T)
                acc[T] = __builtin_amdgcn_mfma_f32_16x16x32_bf16(a1[T], b1, kz, 0, 0, 0);

            // ---- L1 gates (merged-rcp) + state writes ----
            float hn[5];
            #pragma unroll
            for (int T = 0; T < 5; ++T) lstm_unit(acc[T], c1s[T], hn[T]);
            #pragma unroll
            for (int T = 0; T < 5; ++T) {
                stw[b16][4 * T + q]      = hn[T];
                stw[b16][24 + 4 * T + q] = c1s[T];
            }
            if (q == 1) { stw[b16][20] = mu_t; stw[b16][21] = (float)t; }

            // ---- unified state reads: raw -> next b1, lrelu'd -> L2 ----
            f32x4 u0 = *reinterpret_cast<const f32x4*>(&stw[b16][4 * q]);
            f32x4 u1 = *reinterpret_cast<const f32x4*>(&stw[b16][16 + 4 * q]);
            f32x4 u2 = *reinterpret_cast<const f32x4*>(&stw[b16][32 + 4 * q]);
            b1 = pack8v(u0, u1);                             // L1 input for t+1
            f32x4 l0, l1, l2;
            #pragma unroll
            for (int i = 0; i < 4; ++i) {
                l0[i] = lrelu(u0[i]);
                l1[i] = lrelu(u1[i]);
                l2[i] = (q < 3) ? lrelu(u2[i]) : u2[i];      // q3: h2a,h2b,one,zero raw
            }
            bf16x8 b2a = pack8v(l0, l1);
            unsigned p0 = cvt_pk(l2[0], l2[1]), p1 = cvt_pk(l2[2], l2[3]);
            i32x4 tdup = {(int)p0, (int)p1, (int)p0, (int)p1};   // k>=48: A zero
            bf16x8 b2b = __builtin_bit_cast(bf16x8, tdup);

            f32x4 g2 = __builtin_amdgcn_mfma_f32_16x16x32_bf16(a2f[0], b2a, kz, 0, 0, 0);
            g2 = __builtin_amdgcn_mfma_f32_16x16x32_bf16(a2f[1], b2b, g2, 0, 0, 0);

            // ---- L2 gates: q0 = unit a, q1 = unit b (parallel) ----
            float h2;
            lstm_unit(g2, c2, h2);
            if (q < 2) stw[b16][44 + q] = h2;
            float h2o = __shfl_xor(h2, 16);                  // q0 <- h2b

            if (q == 0) {
                obw[0][b16][ti] = h2;                                      // mu_r
                obw[1][b16][ti] = h2o;                                     // lv_r
                obw[2][b16][ti] = fmaf(eps_t, ex2(0.5f * LOG2E * h2o), h2);
            }
        }

        // ---- dump 16 timesteps, coalesced 64B rows ----
        {
            int bq = lane >> 2, ch = lane & 3;
            #pragma unroll
            for (int o = 0; o < 3; ++o) {
                f32x4 v = *reinterpret_cast<const f32x4*>(&obw[o][bq][ch * 4]);
                float* dst = out + (size_t)o * BB * LL + (size_t)(gb0 + bq) * LL
                           + tb * 16 + ch * 4;
                *(float4*)dst = make_float4(v[0], v[1], v[2], v[3]);
            }
        }
    }
}

extern "C" void kernel_launch(void* const* d_in, const int* in_sizes, int n_in,
                              void* d_out, int out_size, void* d_ws, size_t ws_size,
                              hipStream_t stream) {
    sampler_lstm<<<dim3(BB / 64), dim3(256), 0, stream>>>(
        (const float*)d_in[0],  (const float*)d_in[1],  (const float*)d_in[2],
        (const float*)d_in[3],  (const float*)d_in[4],  (const float*)d_in[5],
        (const float*)d_in[6],  (const float*)d_in[7],  (const float*)d_in[8],
        (const float*)d_in[9],  (const float*)d_in[10], (const float*)d_in[11],
        (float*)d_out);
}

// Round 13
// 263.074 us; speedup vs baseline: 21.7798x; 1.0263x over previous
//
#include <hip/hip_runtime.h>

#define BB 65536
#define LL 128
#define HH 20
#define LOG2E 1.4426950408889634f

typedef __attribute__((ext_vector_type(8))) short  bf16x8;
typedef __attribute__((ext_vector_type(4))) float  f32x4;
typedef __attribute__((ext_vector_type(2))) float  f32x2;
typedef __attribute__((ext_vector_type(4))) int    i32x4;

__device__ __forceinline__ float frcp(float x)  { return __builtin_amdgcn_rcpf(x); }
__device__ __forceinline__ float ex2(float x)   { return __builtin_amdgcn_exp2f(x); }
__device__ __forceinline__ float lrelu(float x) { return fmaxf(x, 0.01f * x); }
__device__ __forceinline__ float csign(float mag, float sgn) {   // v_bfi_b32
    int m = __builtin_bit_cast(int, mag), s = __builtin_bit_cast(int, sgn);
    return __builtin_bit_cast(float, (m & 0x7fffffff) | (s & 0x80000000));
}
__device__ __forceinline__ unsigned cvt_pk(float lo, float hi) {
    unsigned r;
    asm("v_cvt_pk_bf16_f32 %0, %1, %2" : "=v"(r) : "v"(lo), "v"(hi));
    return r;
}
__device__ __forceinline__ bf16x8 pack8v(f32x4 a, f32x4 b) {
    i32x4 t = { (int)cvt_pk(a[0], a[1]), (int)cvt_pk(a[2], a[3]),
                (int)cvt_pk(b[0], b[1]), (int)cvt_pk(b[2], b[3]) };
    return __builtin_bit_cast(bf16x8, t);
}

// Merged-rcp LSTM unit (scalar): 5 exp2 + 2 rcp; c,h true values,
// pre-activations a pre-scaled by log2e.
__device__ __forceinline__ void lstm_unit(f32x4 a, float& c, float& h) {
    float ei  = ex2(-a[0]);
    float ef  = ex2(-a[1]);
    float eo  = ex2(-a[3]);
    float egm = ex2(-fabsf(a[2] + a[2]));
    float numg = 1.f - egm, deng = 1.f + egm;
    float A = 1.f + ef, B = 1.f + ei;
    float P = B * deng;
    float D = P * A;
    float n2 = csign(numg * A, a[2]);
    float cn = fmaf(c, P, n2) * frcp(D);
    c = cn;
    float ecm = ex2(-fabsf(cn * (2.f * LOG2E)));
    float numc = 1.f - ecm;
    float Do = (1.f + eo) * (1.f + ecm);
    h = csign(numc, cn) * frcp(Do);
}

// Pair unit: identical math on two independent units, expressed as PLAIN
// f32x2 vector arithmetic (NO inline asm — R11's hand-written VOP3P asm
// produced NaN garbage). The backend selects v_pk_{add,mul,fma}_f32 where
// it can; worst case it scalarizes to exactly the R10 stream (correct
// either way). Trans + csign stay scalar per element (no packed forms).
__device__ __forceinline__ void lstm_unit2(f32x4 a0, f32x4 a1, f32x2& c, f32x2& h) {
    f32x2 gg = {a0[2], a1[2]};
    f32x2 ei  = {ex2(-a0[0]), ex2(-a1[0])};
    f32x2 ef  = {ex2(-a0[1]), ex2(-a1[1])};
    f32x2 eo  = {ex2(-a0[3]), ex2(-a1[3])};
    f32x2 tg  = gg + gg;
    f32x2 egm = {ex2(-fabsf(tg[0])), ex2(-fabsf(tg[1]))};
    f32x2 numg = 1.f - egm;
    f32x2 deng = 1.f + egm;
    f32x2 A = 1.f + ef, B = 1.f + ei;
    f32x2 P = B * deng;
    f32x2 D = P * A;
    f32x2 nA = numg * A;
    f32x2 n2 = {csign(nA[0], gg[0]), csign(nA[1], gg[1])};
    f32x2 rD = {frcp(D[0]), frcp(D[1])};
    f32x2 cn = (c * P + n2) * rD;
    c = cn;
    f32x2 tc = cn * (2.f * LOG2E);
    f32x2 ecm = {ex2(-fabsf(tc[0])), ex2(-fabsf(tc[1]))};
    f32x2 numc = 1.f - ecm;
    f32x2 Do = (1.f + eo) * (1.f + ecm);
    f32x2 rDo = {frcp(Do[0]), frcp(Do[1])};
    f32x2 sc = {csign(numc[0], cn[0]), csign(numc[1], cn[1])};
    h = sc * rDo;
}

// Both layers MFMA; wave = 16 batch elems; b16 = lane&15, q = lane>>4.
// k-slot map s(q,e) = 4q+(e&3)+16(e>>2), consistent for A and B.
// Transposed state st[b16][52]: 0..19 h1 | 20 x0 | 21 x1 | 22 one | 23 zero |
// 24..43 c1 | 44 h2a | 45 h2b | 46 one | 47 zero. Unified read: L2 gather
// doubles as next-step L1 B-frag. 3 ds_read_b128/step, wave-private, no
// barriers. Outputs staged in ob, dumped coalesced every 16 steps.
__global__ __launch_bounds__(256) void sampler_lstm(
    const float* __restrict__ mu, const float* __restrict__ log_var,
    const float* __restrict__ eps0, const float* __restrict__ eps,
    const float* __restrict__ Wih1, const float* __restrict__ Whh1,
    const float* __restrict__ bih1, const float* __restrict__ bhh1,
    const float* __restrict__ Wih2, const float* __restrict__ Whh2,
    const float* __restrict__ bih2, const float* __restrict__ bhh2,
    float* __restrict__ out)
{
    __shared__ __align__(16) float st[4][16][52];
    __shared__ __align__(16) float ob[4][3][16][20];

    const int tid  = threadIdx.x;
    const int wave = tid >> 6;
    const int lane = tid & 63;
    const int b16  = lane & 15;
    const int q    = lane >> 4;
    const int gb0  = (blockIdx.x * 4 + wave) * 16;
    const int gb   = gb0 + b16;

    float (*stw)[52]     = st[wave];
    float (*obw)[16][20] = ob[wave];

    // ---- L1 weight A-frags ----
    bf16x8 a1[5];
    #pragma unroll
    for (int T = 0; T < 5; ++T) {
        int G = 16 * T + b16;
        int j = G >> 2, g = G & 3;
        int row = g * HH + j;
        float v[8];
        #pragma unroll
        for (int e = 0; e < 8; ++e) {
            int k = 4 * q + (e & 3) + 16 * (e >> 2);
            float val;
            if (k < 20)       val = Whh1[row * HH + k];
            else if (k == 20) val = Wih1[row * 2 + 0];
            else if (k == 21) val = Wih1[row * 2 + 1];
            else if (k == 22) val = bih1[row] + bhh1[row];
            else              val = 0.f;
            v[e] = val * LOG2E;
        }
        f32x4 lo = {v[0], v[1], v[2], v[3]}, hi4 = {v[4], v[5], v[6], v[7]};
        a1[T] = pack8v(lo, hi4);
    }
    // ---- L2 weight A-frags: rows m = 4u+p (unit-major), orig row = 2p+u ----
    bf16x8 a2f[2];
    #pragma unroll
    for (int f = 0; f < 2; ++f) {
        float v[8];
        #pragma unroll
        for (int e = 0; e < 8; ++e) {
            int k = 32 * f + 4 * q + (e & 3) + 16 * (e >> 2);
            float val = 0.f;
            if (b16 < 8) {
                int u = b16 >> 2, p = b16 & 3;
                int ro = 2 * p + u;
                if (k < 20)       val = Wih2[ro * 40 + k];
                else if (k < 24)  val = 0.f;
                else if (k < 44)  val = Wih2[ro * 40 + 20 + (k - 24)];
                else if (k == 44) val = Whh2[ro * 2 + 0];
                else if (k == 45) val = Whh2[ro * 2 + 1];
                else if (k == 46) val = bih2[ro] + bhh2[ro];
            }
            v[e] = val * LOG2E;
        }
        f32x4 lo = {v[0], v[1], v[2], v[3]}, hi4 = {v[4], v[5], v[6], v[7]};
        a2f[f] = pack8v(lo, hi4);
    }

    // ---- init state ----
    const float* murow = mu + (size_t)gb * LL;
    float samp0 = eps0[gb] * ex2(0.5f * LOG2E * log_var[(size_t)gb * LL]) + murow[0];
    #pragma unroll
    for (int d = 0; d < 13; ++d) {
        int col = 13 * q + d;
        stw[b16][col] = (col == 20) ? samp0 : (col == 22 || col == 46) ? 1.f : 0.f;
    }

    const f32x4 kz = {0.f, 0.f, 0.f, 0.f};
    f32x2 c01 = {0.f, 0.f}, c23 = {0.f, 0.f};
    float c4 = 0.f, c2 = 0.f;

    // prologue: L1 B-frag for t=0
    bf16x8 b1;
    {
        f32x4 v0 = *reinterpret_cast<const f32x4*>(&stw[b16][4 * q]);
        f32x4 v1 = *reinterpret_cast<const f32x4*>(&stw[b16][16 + 4 * q]);
        b1 = pack8v(v0, v1);
    }

    #pragma unroll 1
    for (int tb = 0; tb < 8; ++tb) {
        #pragma unroll 2
        for (int ti = 0; ti < 16; ++ti) {
            const int t = tb * 16 + ti;
            const float mu_t  = murow[t];
            const float eps_t = eps[(size_t)t * BB + gb];

            // ---- L1: 5 MFMAs ----
            f32x4 acc[5];
            #pragma unroll
            for (int T = 0; T < 5; ++T)
                acc[T] = __builtin_amdgcn_mfma_f32_16x16x32_bf16(a1[T], b1, kz, 0, 0, 0);

            // ---- L1 gates: packed pairs (vector f32x2, no asm) + scalar T4 ----
            f32x2 h01, h23;
            float h4;
            lstm_unit2(acc[0], acc[1], c01, h01);
            lstm_unit2(acc[2], acc[3], c23, h23);
            lstm_unit(acc[4], c4, h4);

            stw[b16][q]      = h01[0];
            stw[b16][4 + q]  = h01[1];
            stw[b16][8 + q]  = h23[0];
            stw[b16][12 + q] = h23[1];
            stw[b16][16 + q] = h4;
            stw[b16][24 + q] = c01[0];
            stw[b16][28 + q] = c01[1];
            stw[b16][32 + q] = c23[0];
            stw[b16][36 + q] = c23[1];
            stw[b16][40 + q] = c4;
            if (q == 1) { stw[b16][20] = mu_t; stw[b16][21] = (float)t; }

            // ---- unified reads: raw -> next b1, lrelu'd -> L2 ----
            f32x4 u0 = *reinterpret_cast<const f32x4*>(&stw[b16][4 * q]);
            f32x4 u1 = *reinterpret_cast<const f32x4*>(&stw[b16][16 + 4 * q]);
            f32x4 u2 = *reinterpret_cast<const f32x4*>(&stw[b16][32 + 4 * q]);
            b1 = pack8v(u0, u1);                             // L1 input for t+1

            f32x4 l0, l1, l2;
            #pragma unroll
            for (int i = 0; i < 4; ++i) {
                l0[i] = lrelu(u0[i]);
                l1[i] = lrelu(u1[i]);
                l2[i] = (q < 3) ? lrelu(u2[i]) : u2[i];      // q3: h2a,h2b,one,zero raw
            }
            bf16x8 b2a = pack8v(l0, l1);
            unsigned p0 = cvt_pk(l2[0], l2[1]), p1 = cvt_pk(l2[2], l2[3]);
            i32x4 tdup = {(int)p0, (int)p1, (int)p0, (int)p1};   // k>=48: A zero
            bf16x8 b2b = __builtin_bit_cast(bf16x8, tdup);

            f32x4 g2 = __builtin_amdgcn_mfma_f32_16x16x32_bf16(a2f[0], b2a, kz, 0, 0, 0);
            g2 = __builtin_amdgcn_mfma_f32_16x16x32_bf16(a2f[1], b2b, g2, 0, 0, 0);

            // ---- L2 gates: q0 = unit a, q1 = unit b ----
            float h2;
            lstm_unit(g2, c2, h2);
            if (q < 2) stw[b16][44 + q] = h2;
            float h2o = __shfl_xor(h2, 16);                  // q0 <- h2b

            if (q == 0) {
                obw[0][b16][ti] = h2;
                obw[1][b16][ti] = h2o;
                obw[2][b16][ti] = fmaf(eps_t, ex2(0.5f * LOG2E * h2o), h2);
            }
        }

        // ---- dump 16 timesteps, coalesced 64B rows ----
        {
            int bq = lane >> 2, ch = lane & 3;
            #pragma unroll
            for (int o = 0; o < 3; ++o) {
                f32x4 v = *reinterpret_cast<const f32x4*>(&obw[o][bq][ch * 4]);
                float* dst = out + (size_t)o * BB * LL + (size_t)(gb0 + bq) * LL
                           + tb * 16 + ch * 4;
                *(float4*)dst = make_float4(v[0], v[1], v[2], v[3]);
            }
        }
    }
}

extern "C" void kernel_launch(void* const* d_in, const int* in_sizes, int n_in,
                              void* d_out, int out_size, void* d_ws, size_t ws_size,
                              hipStream_t stream) {
    sampler_lstm<<<dim3(BB / 64), dim3(256), 0, stream>>>(
        (const float*)d_in[0],  (const float*)d_in[1],  (const float*)d_in[2],
        (const float*)d_in[3],  (const float*)d_in[4],  (const float*)d_in[5],
        (const float*)d_in[6],  (const float*)d_in[7],  (const float*)d_in[8],
        (const float*)d_in[9],  (const float*)d_in[10], (const float*)d_in[11],
        (float*)d_out);
}

// Round 14
// 257.208 us; speedup vs baseline: 22.2765x; 1.0228x over previous
//
#include <hip/hip_runtime.h>

#define BB 65536
#define LL 128
#define HH 20
#define LOG2E 1.4426950408889634f

typedef __attribute__((ext_vector_type(8))) short  bf16x8;
typedef __attribute__((ext_vector_type(4))) float  f32x4;
typedef __attribute__((ext_vector_type(2))) float  f32x2;
typedef __attribute__((ext_vector_type(4))) int    i32x4;

__device__ __forceinline__ float frcp(float x)  { return __builtin_amdgcn_rcpf(x); }
__device__ __forceinline__ float ex2(float x)   { return __builtin_amdgcn_exp2f(x); }
__device__ __forceinline__ float lrelu(float x) { return fmaxf(x, 0.01f * x); }
__device__ __forceinline__ float csign(float mag, float sgn) {   // v_bfi_b32
    int m = __builtin_bit_cast(int, mag), s = __builtin_bit_cast(int, sgn);
    return __builtin_bit_cast(float, (m & 0x7fffffff) | (s & 0x80000000));
}
__device__ __forceinline__ unsigned cvt_pk(float lo, float hi) {
    unsigned r;
    asm("v_cvt_pk_bf16_f32 %0, %1, %2" : "=v"(r) : "v"(lo), "v"(hi));
    return r;
}
__device__ __forceinline__ bf16x8 pack8v(f32x4 a, f32x4 b) {
    i32x4 t = { (int)cvt_pk(a[0], a[1]), (int)cvt_pk(a[2], a[3]),
                (int)cvt_pk(b[0], b[1]), (int)cvt_pk(b[2], b[3]) };
    return __builtin_bit_cast(bf16x8, t);
}

// Merged-rcp LSTM unit (scalar): 5 exp2 + 2 rcp. NOTE: per-unit rcp kept
// deliberately — pair-merging denominators overflows f32 (D0*D1 ~ 1e56 when
// x1 = t <= 127 pushes pre-activations to +-35).
__device__ __forceinline__ void lstm_unit(f32x4 a, float& c, float& h) {
    float ei  = ex2(-a[0]);
    float ef  = ex2(-a[1]);
    float eo  = ex2(-a[3]);
    float egm = ex2(-fabsf(a[2] + a[2]));
    float numg = 1.f - egm, deng = 1.f + egm;
    float A = 1.f + ef, B = 1.f + ei;
    float P = B * deng;
    float D = P * A;
    float n2 = csign(numg * A, a[2]);
    float cn = fmaf(c, P, n2) * frcp(D);
    c = cn;
    float ecm = ex2(-fabsf(cn * (2.f * LOG2E)));
    float numc = 1.f - ecm;
    float Do = (1.f + eo) * (1.f + ecm);
    h = csign(numc, cn) * frcp(Do);
}

// Pair unit: plain f32x2 vector arithmetic (backend selects v_pk_*_f32).
__device__ __forceinline__ void lstm_unit2(f32x4 a0, f32x4 a1, f32x2& c, f32x2& h) {
    f32x2 gg = {a0[2], a1[2]};
    f32x2 ei  = {ex2(-a0[0]), ex2(-a1[0])};
    f32x2 ef  = {ex2(-a0[1]), ex2(-a1[1])};
    f32x2 eo  = {ex2(-a0[3]), ex2(-a1[3])};
    f32x2 tg  = gg + gg;
    f32x2 egm = {ex2(-fabsf(tg[0])), ex2(-fabsf(tg[1]))};
    f32x2 numg = 1.f - egm;
    f32x2 deng = 1.f + egm;
    f32x2 A = 1.f + ef, B = 1.f + ei;
    f32x2 P = B * deng;
    f32x2 D = P * A;
    f32x2 nA = numg * A;
    f32x2 n2 = {csign(nA[0], gg[0]), csign(nA[1], gg[1])};
    f32x2 rD = {frcp(D[0]), frcp(D[1])};
    f32x2 cn = (c * P + n2) * rD;
    c = cn;
    f32x2 tc = cn * (2.f * LOG2E);
    f32x2 ecm = {ex2(-fabsf(tc[0])), ex2(-fabsf(tc[1]))};
    f32x2 numc = 1.f - ecm;
    f32x2 Do = (1.f + eo) * (1.f + ecm);
    f32x2 rDo = {frcp(Do[0]), frcp(Do[1])};
    f32x2 sc = {csign(numc[0], cn[0]), csign(numc[1], cn[1])};
    h = sc * rDo;
}

// Both layers MFMA; wave = 16 batch elems; b16 = lane&15, q = lane>>4.
// k-slot -> LDS col relabel (contraction-invariant; A built to match):
//   slot k -> col 8*((k&12)>>2) + (k&3) + 4*(k>>4)   [within each 32-k frag]
// State row st[b16][68] (stride 68 floats = 272B, every b128 16B-aligned;
// bank histogram of any b128 read/write is exactly 8 hits/bank = balanced):
//   frag0 region cols 0..31:  h unit j=4T+q at col 8q+T | x0@5 x1@6 one@7 |
//                             zeros at 8q+5..7 (q>0)
//   frag1 region cols 32..63: c unit j=4T+q at col 32+8q+T | h2a@37 h2b@38
//                             one@39 | zeros elsewhere
// Writes: each lane's 5 h (and 5 c) are contiguous -> b128+b32 each.
// Unified read: cols 8q..8q+7 feed BOTH next-step L1 B-frag (raw) and L2
// frag0 (lrelu'd). One merged global load/step (q1: mu, others: eps).
// All LDS wave-private, zero barriers after init. Outputs staged in ob,
// dumped coalesced every 16 steps.
__global__ __launch_bounds__(256) void sampler_lstm(
    const float* __restrict__ mu, const float* __restrict__ log_var,
    const float* __restrict__ eps0, const float* __restrict__ eps,
    const float* __restrict__ Wih1, const float* __restrict__ Whh1,
    const float* __restrict__ bih1, const float* __restrict__ bhh1,
    const float* __restrict__ Wih2, const float* __restrict__ Whh2,
    const float* __restrict__ bih2, const float* __restrict__ bhh2,
    float* __restrict__ out)
{
    __shared__ __align__(16) float st[4][16][68];
    __shared__ __align__(16) float ob[4][3][16][20];

    const int tid  = threadIdx.x;
    const int wave = tid >> 6;
    const int lane = tid & 63;
    const int b16  = lane & 15;
    const int q    = lane >> 4;
    const int gb0  = (blockIdx.x * 4 + wave) * 16;
    const int gb   = gb0 + b16;

    float (*stw)[68]     = st[wave];
    float (*obw)[16][20] = ob[wave];

    // ---- L1 weight A-frags (col map: e<4 -> h_{4e+q}; e==4 -> h_{16+q};
    //      e in 5..7 & q==0 -> x0,x1,bias; else 0) ----
    bf16x8 a1[5];
    #pragma unroll
    for (int T = 0; T < 5; ++T) {
        int G = 16 * T + b16;
        int j = G >> 2, g = G & 3;
        int row = g * HH + j;
        float v[8];
        #pragma unroll
        for (int e = 0; e < 8; ++e) {
            float val = 0.f;
            if (e < 4)        val = Whh1[row * HH + 4 * e + q];
            else if (e == 4)  val = Whh1[row * HH + 16 + q];
            else if (q == 0) {
                if (e == 5)      val = Wih1[row * 2 + 0];
                else if (e == 6) val = Wih1[row * 2 + 1];
                else             val = bih1[row] + bhh1[row];
            }
            v[e] = val * LOG2E;
        }
        f32x4 lo = {v[0], v[1], v[2], v[3]}, hi4 = {v[4], v[5], v[6], v[7]};
        a1[T] = pack8v(lo, hi4);
    }
    // ---- L2 weight A-frags: rows m = 4u+p (unit-major), orig row = 2p+u ----
    bf16x8 a2f[2];
    #pragma unroll
    for (int f = 0; f < 2; ++f) {
        float v[8];
        #pragma unroll
        for (int e = 0; e < 8; ++e) {
            float val = 0.f;
            if (b16 < 8) {
                int u = b16 >> 2, p = b16 & 3;
                int ro = 2 * p + u;
                if (f == 0) {
                    if (e < 4)       val = Wih2[ro * 40 + 4 * e + q];
                    else if (e == 4) val = Wih2[ro * 40 + 16 + q];
                } else {
                    if (e < 4)       val = Wih2[ro * 40 + 20 + 4 * e + q];
                    else if (e == 4) val = Wih2[ro * 40 + 36 + q];
                    else if (q == 0) {
                        if (e == 5)      val = Whh2[ro * 2 + 0];
                        else if (e == 6) val = Whh2[ro * 2 + 1];
                        else             val = bih2[ro] + bhh2[ro];
                    }
                }
            }
            v[e] = val * LOG2E;
        }
        f32x4 lo = {v[0], v[1], v[2], v[3]}, hi4 = {v[4], v[5], v[6], v[7]};
        a2f[f] = pack8v(lo, hi4);
    }

    // ---- init state (zero all 68 cols, then specials) ----
    const float* murow = mu + (size_t)gb * LL;
    float samp0 = eps0[gb] * ex2(0.5f * LOG2E * log_var[(size_t)gb * LL]) + murow[0];
    #pragma unroll
    for (int d = 0; d < 17; ++d) stw[b16][17 * q + d] = 0.f;
    if (q == 0) { stw[b16][5] = samp0; stw[b16][7] = 1.f; stw[b16][39] = 1.f; }

    // ---- merged per-step global load: q1 reads mu, others read eps ----
    const float* rp = (q == 1) ? murow : (eps + gb);
    const size_t rstride = (q == 1) ? 1 : (size_t)BB;

    const f32x4 kz = {0.f, 0.f, 0.f, 0.f};
    f32x2 c01 = {0.f, 0.f}, c23 = {0.f, 0.f};
    float c4 = 0.f, c2 = 0.f;

    // prologue: L1 B-frag for t=0
    bf16x8 b1;
    {
        f32x4 v0 = *reinterpret_cast<const f32x4*>(&stw[b16][8 * q]);
        f32x4 v1 = *reinterpret_cast<const f32x4*>(&stw[b16][8 * q + 4]);
        b1 = pack8v(v0, v1);
    }

    #pragma unroll 1
    for (int tb = 0; tb < 8; ++tb) {
        #pragma unroll 2
        for (int ti = 0; ti < 16; ++ti) {
            const int t = tb * 16 + ti;
            const float ldv = *rp;           // q1: mu_t ; q0/2/3: eps_t
            rp += rstride;

            // ---- L1: 5 MFMAs ----
            f32x4 acc[5];
            #pragma unroll
            for (int T = 0; T < 5; ++T)
                acc[T] = __builtin_amdgcn_mfma_f32_16x16x32_bf16(a1[T], b1, kz, 0, 0, 0);

            // ---- L1 gates ----
            f32x2 h01, h23;
            float h4;
            lstm_unit2(acc[0], acc[1], c01, h01);
            lstm_unit2(acc[2], acc[3], c23, h23);
            lstm_unit(acc[4], c4, h4);

            // ---- packed state writes (aligned b128 + b32 each) ----
            f32x4 hv = {h01[0], h01[1], h23[0], h23[1]};
            f32x4 cv = {c01[0], c01[1], c23[0], c23[1]};
            *reinterpret_cast<f32x4*>(&stw[b16][8 * q]) = hv;
            stw[b16][8 * q + 4] = h4;
            *reinterpret_cast<f32x4*>(&stw[b16][32 + 8 * q]) = cv;
            stw[b16][32 + 8 * q + 4] = c4;
            if (q == 1) { stw[b16][5] = ldv; stw[b16][6] = (float)t; }

            // ---- unified reads: raw -> next b1; lrelu'd -> L2 frags ----
            f32x4 u0 = *reinterpret_cast<const f32x4*>(&stw[b16][8 * q]);
            f32x4 u1 = *reinterpret_cast<const f32x4*>(&stw[b16][8 * q + 4]);
            f32x4 u2 = *reinterpret_cast<const f32x4*>(&stw[b16][32 + 8 * q]);
            f32x4 u3 = *reinterpret_cast<const f32x4*>(&stw[b16][32 + 8 * q + 4]);
            b1 = pack8v(u0, u1);                         // L1 input for t+1

            f32x4 l0, l1, l2, l3;
            #pragma unroll
            for (int i = 0; i < 4; ++i) {
                l0[i] = lrelu(u0[i]);
                l1[i] = lrelu(u1[i]);
                l2[i] = lrelu(u2[i]);
            }
            l3[0] = lrelu(u3[0]);                        // c_{16+q}
            l3[1] = u3[1]; l3[2] = u3[2]; l3[3] = u3[3]; // h2a,h2b,one (q0) / zeros

            bf16x8 b2a = pack8v(l0, l1);
            bf16x8 b2b = pack8v(l2, l3);

            f32x4 g2 = __builtin_amdgcn_mfma_f32_16x16x32_bf16(a2f[0], b2a, kz, 0, 0, 0);
            g2 = __builtin_amdgcn_mfma_f32_16x16x32_bf16(a2f[1], b2b, g2, 0, 0, 0);

            // ---- L2 gates: q0 = unit a, q1 = unit b ----
            float h2;
            lstm_unit(g2, c2, h2);
            if (q < 2) stw[b16][37 + q] = h2;
            float h2o = __shfl_xor(h2, 16);              // q0 <- h2b

            if (q == 0) {
                obw[0][b16][ti] = h2;
                obw[1][b16][ti] = h2o;
                obw[2][b16][ti] = fmaf(ldv, ex2(0.5f * LOG2E * h2o), h2);
            }
        }

        // ---- dump 16 timesteps, coalesced 64B rows ----
        {
            int bq = lane >> 2, ch = lane & 3;
            #pragma unroll
            for (int o = 0; o < 3; ++o) {
                f32x4 v = *reinterpret_cast<const f32x4*>(&obw[o][bq][ch * 4]);
                float* dst = out + (size_t)o * BB * LL + (size_t)(gb0 + bq) * LL
                           + tb * 16 + ch * 4;
                *(float4*)dst = make_float4(v[0], v[1], v[2], v[3]);
            }
        }
    }
}

extern "C" void kernel_launch(void* const* d_in, const int* in_sizes, int n_in,
                              void* d_out, int out_size, void* d_ws, size_t ws_size,
                              hipStream_t stream) {
    sampler_lstm<<<dim3(BB / 64), dim3(256), 0, stream>>>(
        (const float*)d_in[0],  (const float*)d_in[1],  (const float*)d_in[2],
        (const float*)d_in[3],  (const float*)d_in[4],  (const float*)d_in[5],
        (const float*)d_in[6],  (const float*)d_in[7],  (const float*)d_in[8],
        (const float*)d_in[9],  (const float*)d_in[10], (const float*)d_in[11],
        (float*)d_out);
}

// Round 15
// 237.871 us; speedup vs baseline: 24.0874x; 1.0813x over previous
//
#include <hip/hip_runtime.h>

#define BB 65536
#define LL 128
#define HH 20
#define LOG2E 1.4426950408889634f

typedef __attribute__((ext_vector_type(8))) short  bf16x8;
typedef __attribute__((ext_vector_type(4))) float  f32x4;
typedef __attribute__((ext_vector_type(2))) float  f32x2;
typedef __attribute__((ext_vector_type(4))) int    i32x4;

__device__ __forceinline__ float frcp(float x)  { return __builtin_amdgcn_rcpf(x); }
__device__ __forceinline__ float ex2(float x)   { return __builtin_amdgcn_exp2f(x); }
__device__ __forceinline__ float lrelu(float x) { return fmaxf(x, 0.01f * x); }
__device__ __forceinline__ float csign(float mag, float sgn) {   // v_bfi_b32
    int m = __builtin_bit_cast(int, mag), s = __builtin_bit_cast(int, sgn);
    return __builtin_bit_cast(float, (m & 0x7fffffff) | (s & 0x80000000));
}
__device__ __forceinline__ unsigned cvt_pk(float lo, float hi) {
    unsigned r;
    asm("v_cvt_pk_bf16_f32 %0, %1, %2" : "=v"(r) : "v"(lo), "v"(hi));
    return r;
}
__device__ __forceinline__ bf16x8 pack8v(f32x4 a, f32x4 b) {
    i32x4 t = { (int)cvt_pk(a[0], a[1]), (int)cvt_pk(a[2], a[3]),
                (int)cvt_pk(b[0], b[1]), (int)cvt_pk(b[2], b[3]) };
    return __builtin_bit_cast(bf16x8, t);
}

// Merged-rcp LSTM unit (scalar): 5 exp2 + 2 rcp. Per-unit rcp kept
// deliberately — pair-merging denominators overflows f32.
__device__ __forceinline__ void lstm_unit(f32x4 a, float& c, float& h) {
    float ei  = ex2(-a[0]);
    float ef  = ex2(-a[1]);
    float eo  = ex2(-a[3]);
    float egm = ex2(-fabsf(a[2] + a[2]));
    float numg = 1.f - egm, deng = 1.f + egm;
    float A = 1.f + ef, B = 1.f + ei;
    float P = B * deng;
    float D = P * A;
    float n2 = csign(numg * A, a[2]);
    float cn = fmaf(c, P, n2) * frcp(D);
    c = cn;
    float ecm = ex2(-fabsf(cn * (2.f * LOG2E)));
    float numc = 1.f - ecm;
    float Do = (1.f + eo) * (1.f + ecm);
    h = csign(numc, cn) * frcp(Do);
}

// Pair unit: plain f32x2 vector arithmetic (backend selects v_pk_*_f32).
__device__ __forceinline__ void lstm_unit2(f32x4 a0, f32x4 a1, f32x2& c, f32x2& h) {
    f32x2 gg = {a0[2], a1[2]};
    f32x2 ei  = {ex2(-a0[0]), ex2(-a1[0])};
    f32x2 ef  = {ex2(-a0[1]), ex2(-a1[1])};
    f32x2 eo  = {ex2(-a0[3]), ex2(-a1[3])};
    f32x2 tg  = gg + gg;
    f32x2 egm = {ex2(-fabsf(tg[0])), ex2(-fabsf(tg[1]))};
    f32x2 numg = 1.f - egm;
    f32x2 deng = 1.f + egm;
    f32x2 A = 1.f + ef, B = 1.f + ei;
    f32x2 P = B * deng;
    f32x2 D = P * A;
    f32x2 nA = numg * A;
    f32x2 n2 = {csign(nA[0], gg[0]), csign(nA[1], gg[1])};
    f32x2 rD = {frcp(D[0]), frcp(D[1])};
    f32x2 cn = (c * P + n2) * rD;
    c = cn;
    f32x2 tc = cn * (2.f * LOG2E);
    f32x2 ecm = {ex2(-fabsf(tc[0])), ex2(-fabsf(tc[1]))};
    f32x2 numc = 1.f - ecm;
    f32x2 Do = (1.f + eo) * (1.f + ecm);
    f32x2 rDo = {frcp(Do[0]), frcp(Do[1])};
    f32x2 sc = {csign(numc[0], cn[0]), csign(numc[1], cn[1])};
    h = sc * rDo;
}

// Both layers MFMA; wave = 16 batch elems; b16 = lane&15, q = lane>>4.
// REGISTER-RESIDENT STATE (R13 lesson): under the R13 k-relabel
// (logical col(q,e) = 8q+e; A built to match), the B-frag slots of lane
// (b16,q) are exactly the h/c units j = 4T+q that THIS lane computed
// (acc[T] -> hn[T], c1s[T]). The state LDS round-trip was a self-copy, so
// the loop now builds all MFMA B operands straight from registers:
//   b1  = pack({hn0..3},{hn4, xA, xB, 1})        xA=mu_{t-1}, xB=t-1 (q0;
//                                                q>0 slots have A=0 -> don't care)
//   b2a = pack(lrelu(hn0..3), {lrelu(hn4),...})  frag0 e>=5: A=0
//   b2b = pack(lrelu(c0..3), {lrelu(c4), h2self, h2oth, 1})  (q0 slots live)
// Cross-lane traffic per step: ONE shfl_xor (h2b). Zero loop LDS except
// output staging ob (q0 writes; 2-way bank aliasing = free), dumped as
// coalesced 64B rows every 16 steps. No barriers after init.
__global__ __launch_bounds__(256) void sampler_lstm(
    const float* __restrict__ mu, const float* __restrict__ log_var,
    const float* __restrict__ eps0, const float* __restrict__ eps,
    const float* __restrict__ Wih1, const float* __restrict__ Whh1,
    const float* __restrict__ bih1, const float* __restrict__ bhh1,
    const float* __restrict__ Wih2, const float* __restrict__ Whh2,
    const float* __restrict__ bih2, const float* __restrict__ bhh2,
    float* __restrict__ out)
{
    __shared__ __align__(16) float ob[4][3][16][20];

    const int tid  = threadIdx.x;
    const int wave = tid >> 6;
    const int lane = tid & 63;
    const int b16  = lane & 15;
    const int q    = lane >> 4;
    const int gb0  = (blockIdx.x * 4 + wave) * 16;
    const int gb   = gb0 + b16;

    float (*obw)[16][20] = ob[wave];

    // ---- L1 weight A-frags (logical col 8q+e; e<4 -> Whh1 col 4e+q,
    //      e==4 -> col 16+q, q0 e=5,6,7 -> Wih1 c0, c1, bias) ----
    bf16x8 a1[5];
    #pragma unroll
    for (int T = 0; T < 5; ++T) {
        int G = 16 * T + b16;
        int j = G >> 2, g = G & 3;
        int row = g * HH + j;
        float v[8];
        #pragma unroll
        for (int e = 0; e < 8; ++e) {
            float val = 0.f;
            if (e < 4)        val = Whh1[row * HH + 4 * e + q];
            else if (e == 4)  val = Whh1[row * HH + 16 + q];
            else if (q == 0) {
                if (e == 5)      val = Wih1[row * 2 + 0];
                else if (e == 6) val = Wih1[row * 2 + 1];
                else             val = bih1[row] + bhh1[row];
            }
            v[e] = val * LOG2E;
        }
        f32x4 lo = {v[0], v[1], v[2], v[3]}, hi4 = {v[4], v[5], v[6], v[7]};
        a1[T] = pack8v(lo, hi4);
    }
    // ---- L2 weight A-frags: rows m = 4u+p (unit-major), orig row = 2p+u ----
    bf16x8 a2f[2];
    #pragma unroll
    for (int f = 0; f < 2; ++f) {
        float v[8];
        #pragma unroll
        for (int e = 0; e < 8; ++e) {
            float val = 0.f;
            if (b16 < 8) {
                int u = b16 >> 2, p = b16 & 3;
                int ro = 2 * p + u;
                if (f == 0) {
                    if (e < 4)       val = Wih2[ro * 40 + 4 * e + q];
                    else if (e == 4) val = Wih2[ro * 40 + 16 + q];
                } else {
                    if (e < 4)       val = Wih2[ro * 40 + 20 + 4 * e + q];
                    else if (e == 4) val = Wih2[ro * 40 + 36 + q];
                    else if (q == 0) {
                        if (e == 5)      val = Whh2[ro * 2 + 0];
                        else if (e == 6) val = Whh2[ro * 2 + 1];
                        else             val = bih2[ro] + bhh2[ro];
                    }
                }
            }
            v[e] = val * LOG2E;
        }
        f32x4 lo = {v[0], v[1], v[2], v[3]}, hi4 = {v[4], v[5], v[6], v[7]};
        a2f[f] = pack8v(lo, hi4);
    }

    // ---- init state (all registers) ----
    const float* murow = mu + (size_t)gb * LL;
    float samp0 = eps0[gb] * ex2(0.5f * LOG2E * log_var[(size_t)gb * LL]) + murow[0];

    const f32x4 kz = {0.f, 0.f, 0.f, 0.f};
    f32x2 c01 = {0.f, 0.f}, c23 = {0.f, 0.f};
    float c4 = 0.f, c2 = 0.f;
    float xA = (q == 0) ? samp0 : 0.f;   // x0 (mu_{t-1} after step 0)
    float xB = 0.f;                       // x1 (t-1)
    float h2self = 0.f, h2oth = 0.f;      // own h2 / partner h2 (prev step)

    const float* epsp = eps + gb;

    // prologue: b1 for t=0 (h=0)
    f32x4 zlo = {0.f, 0.f, 0.f, 0.f};
    f32x4 phi = {0.f, xA, xB, 1.f};
    bf16x8 b1 = pack8v(zlo, phi);

    #pragma unroll 1
    for (int tb = 0; tb < 8; ++tb) {
        #pragma unroll 2
        for (int ti = 0; ti < 16; ++ti) {
            const int t = tb * 16 + ti;
            float ldmu = 0.f, ldeps = 0.f;
            if (q == 0) { ldmu = murow[t]; ldeps = *epsp; }
            epsp += BB;

            // ---- L1: 5 MFMAs ----
            f32x4 acc[5];
            #pragma unroll
            for (int T = 0; T < 5; ++T)
                acc[T] = __builtin_amdgcn_mfma_f32_16x16x32_bf16(a1[T], b1, kz, 0, 0, 0);

            // ---- L1 gates (register-resident state) ----
            f32x2 h01, h23;
            float h4;
            lstm_unit2(acc[0], acc[1], c01, h01);
            lstm_unit2(acc[2], acc[3], c23, h23);
            lstm_unit(acc[4], c4, h4);

            // ---- next-step L1 B-frag + L2 B-frags, straight from registers ----
            f32x4 hv = {h01[0], h01[1], h23[0], h23[1]};
            f32x4 cv = {c01[0], c01[1], c23[0], c23[1]};
            f32x4 b1hi = {h4, ldmu, (float)t, 1.f};          // xA,xB for t+1 (q>0: A=0)
            b1 = pack8v(hv, b1hi);

            f32x4 l0 = {lrelu(hv[0]), lrelu(hv[1]), lrelu(hv[2]), lrelu(hv[3])};
            f32x4 l1 = {lrelu(h4), 0.f, 0.f, 0.f};           // e>=5: A=0
            f32x4 l2 = {lrelu(cv[0]), lrelu(cv[1]), lrelu(cv[2]), lrelu(cv[3])};
            f32x4 l3 = {lrelu(c4), h2self, h2oth, 1.f};      // h2a,h2b,one (q0 live)
            bf16x8 b2a = pack8v(l0, l1);
            bf16x8 b2b = pack8v(l2, l3);

            f32x4 g2 = __builtin_amdgcn_mfma_f32_16x16x32_bf16(a2f[0], b2a, kz, 0, 0, 0);
            g2 = __builtin_amdgcn_mfma_f32_16x16x32_bf16(a2f[1], b2b, g2, 0, 0, 0);

            // ---- L2 gates: q0 = unit a, q1 = unit b (parallel) ----
            float h2;
            lstm_unit(g2, c2, h2);
            h2self = h2;
            h2oth  = __shfl_xor(h2, 16);                     // q0 <- h2b (q1's h2)

            if (q == 0) {
                obw[0][b16][ti] = h2;
                obw[1][b16][ti] = h2oth;
                obw[2][b16][ti] = fmaf(ldeps, ex2(0.5f * LOG2E * h2oth), h2);
            }
        }

        // ---- dump 16 timesteps, coalesced 64B rows ----
        {
            int bq = lane >> 2, ch = lane & 3;
            #pragma unroll
            for (int o = 0; o < 3; ++o) {
                f32x4 v = *reinterpret_cast<const f32x4*>(&obw[o][bq][ch * 4]);
                float* dst = out + (size_t)o * BB * LL + (size_t)(gb0 + bq) * LL
                           + tb * 16 + ch * 4;
                *(float4*)dst = make_float4(v[0], v[1], v[2], v[3]);
            }
        }
    }
}

extern "C" void kernel_launch(void* const* d_in, const int* in_sizes, int n_in,
                              void* d_out, int out_size, void* d_ws, size_t ws_size,
                              hipStream_t stream) {
    sampler_lstm<<<dim3(BB / 64), dim3(256), 0, stream>>>(
        (const float*)d_in[0],  (const float*)d_in[1],  (const float*)d_in[2],
        (const float*)d_in[3],  (const float*)d_in[4],  (const float*)d_in[5],
        (const float*)d_in[6],  (const float*)d_in[7],  (const float*)d_in[8],
        (const float*)d_in[9],  (const float*)d_in[10], (const float*)d_in[11],
        (float*)d_out);
}

// Round 16
// 236.608 us; speedup vs baseline: 24.2160x; 1.0053x over previous
//
#include <hip/hip_runtime.h>

#define BB 65536
#define LL 128
#define HH 20
#define LOG2E 1.4426950408889634f

typedef __attribute__((ext_vector_type(8))) short  bf16x8;
typedef __attribute__((ext_vector_type(4))) float  f32x4;
typedef __attribute__((ext_vector_type(2))) float  f32x2;
typedef __attribute__((ext_vector_type(4))) int    i32x4;

__device__ __forceinline__ float frcp(float x)  { return __builtin_amdgcn_rcpf(x); }
__device__ __forceinline__ float ex2(float x)   { return __builtin_amdgcn_exp2f(x); }
__device__ __forceinline__ float lrelu(float x) { return fmaxf(x, 0.01f * x); }
__device__ __forceinline__ float csign(float mag, float sgn) {   // v_bfi_b32
    int m = __builtin_bit_cast(int, mag), s = __builtin_bit_cast(int, sgn);
    return __builtin_bit_cast(float, (m & 0x7fffffff) | (s & 0x80000000));
}
__device__ __forceinline__ unsigned cvt_pk(float lo, float hi) {
    unsigned r;
    asm("v_cvt_pk_bf16_f32 %0, %1, %2" : "=v"(r) : "v"(lo), "v"(hi));
    return r;
}
__device__ __forceinline__ bf16x8 pack8v(f32x4 a, f32x4 b) {
    i32x4 t = { (int)cvt_pk(a[0], a[1]), (int)cvt_pk(a[2], a[3]),
                (int)cvt_pk(b[0], b[1]), (int)cvt_pk(b[2], b[3]) };
    return __builtin_bit_cast(bf16x8, t);
}

// Merged-rcp LSTM unit (scalar): 5 exp2 + 2 rcp. Per-unit rcp kept —
// pair-merging denominators overflows f32.
__device__ __forceinline__ void lstm_unit(f32x4 a, float& c, float& h) {
    float ei  = ex2(-a[0]);
    float ef  = ex2(-a[1]);
    float eo  = ex2(-a[3]);
    float egm = ex2(-fabsf(a[2] + a[2]));
    float numg = 1.f - egm, deng = 1.f + egm;
    float A = 1.f + ef, B = 1.f + ei;
    float P = B * deng;
    float D = P * A;
    float n2 = csign(numg * A, a[2]);
    float cn = fmaf(c, P, n2) * frcp(D);
    c = cn;
    float ecm = ex2(-fabsf(cn * (2.f * LOG2E)));
    float numc = 1.f - ecm;
    float Do = (1.f + eo) * (1.f + ecm);
    h = csign(numc, cn) * frcp(Do);
}

// Pair unit: plain f32x2 vector arithmetic (backend selects v_pk_*_f32).
__device__ __forceinline__ void lstm_unit2(f32x4 a0, f32x4 a1, f32x2& c, f32x2& h) {
    f32x2 gg = {a0[2], a1[2]};
    f32x2 ei  = {ex2(-a0[0]), ex2(-a1[0])};
    f32x2 ef  = {ex2(-a0[1]), ex2(-a1[1])};
    f32x2 eo  = {ex2(-a0[3]), ex2(-a1[3])};
    f32x2 tg  = gg + gg;
    f32x2 egm = {ex2(-fabsf(tg[0])), ex2(-fabsf(tg[1]))};
    f32x2 numg = 1.f - egm;
    f32x2 deng = 1.f + egm;
    f32x2 A = 1.f + ef, B = 1.f + ei;
    f32x2 P = B * deng;
    f32x2 D = P * A;
    f32x2 nA = numg * A;
    f32x2 n2 = {csign(nA[0], gg[0]), csign(nA[1], gg[1])};
    f32x2 rD = {frcp(D[0]), frcp(D[1])};
    f32x2 cn = (c * P + n2) * rD;
    c = cn;
    f32x2 tc = cn * (2.f * LOG2E);
    f32x2 ecm = {ex2(-fabsf(tc[0])), ex2(-fabsf(tc[1]))};
    f32x2 numc = 1.f - ecm;
    f32x2 Do = (1.f + eo) * (1.f + ecm);
    f32x2 rDo = {frcp(Do[0]), frcp(Do[1])};
    f32x2 sc = {csign(numc[0], cn[0]), csign(numc[1], cn[1])};
    h = sc * rDo;
}

// Both layers MFMA; wave = 16 batch elems; b16 = lane&15, q = lane>>4.
// Register-resident state (R14) + DEFERRED L2 GATES (this round): the L2
// MFMA of step t produces g2s, applied during step t+1's gate phase PAIRED
// with T4's unit (3x lstm_unit2, zero scalar units in the loop). h2(t-1)
// is only consumed by b2b(t) and out(t-1) — both built at iteration t, so
// the deferral is exact (bit-identical outputs). Outputs stage one step
// late: slot (t-1)&15, dump at t%16==0 (uniform branch), tail handles
// t=127. Cross-lane traffic: ONE shfl_xor per step. LDS only for staging.
__global__ __launch_bounds__(256) void sampler_lstm(
    const float* __restrict__ mu, const float* __restrict__ log_var,
    const float* __restrict__ eps0, const float* __restrict__ eps,
    const float* __restrict__ Wih1, const float* __restrict__ Whh1,
    const float* __restrict__ bih1, const float* __restrict__ bhh1,
    const float* __restrict__ Wih2, const float* __restrict__ Whh2,
    const float* __restrict__ bih2, const float* __restrict__ bhh2,
    float* __restrict__ out)
{
    __shared__ __align__(16) float ob[4][3][16][20];

    const int tid  = threadIdx.x;
    const int wave = tid >> 6;
    const int lane = tid & 63;
    const int b16  = lane & 15;
    const int q    = lane >> 4;
    const int gb0  = (blockIdx.x * 4 + wave) * 16;
    const int gb   = gb0 + b16;

    float (*obw)[16][20] = ob[wave];

    // ---- L1 weight A-frags (logical col 8q+e) ----
    bf16x8 a1[5];
    #pragma unroll
    for (int T = 0; T < 5; ++T) {
        int G = 16 * T + b16;
        int j = G >> 2, g = G & 3;
        int row = g * HH + j;
        float v[8];
        #pragma unroll
        for (int e = 0; e < 8; ++e) {
            float val = 0.f;
            if (e < 4)        val = Whh1[row * HH + 4 * e + q];
            else if (e == 4)  val = Whh1[row * HH + 16 + q];
            else if (q == 0) {
                if (e == 5)      val = Wih1[row * 2 + 0];
                else if (e == 6) val = Wih1[row * 2 + 1];
                else             val = bih1[row] + bhh1[row];
            }
            v[e] = val * LOG2E;
        }
        f32x4 lo = {v[0], v[1], v[2], v[3]}, hi4 = {v[4], v[5], v[6], v[7]};
        a1[T] = pack8v(lo, hi4);
    }
    // ---- L2 weight A-frags: rows m = 4u+p (unit-major), orig row = 2p+u ----
    bf16x8 a2f[2];
    #pragma unroll
    for (int f = 0; f < 2; ++f) {
        float v[8];
        #pragma unroll
        for (int e = 0; e < 8; ++e) {
            float val = 0.f;
            if (b16 < 8) {
                int u = b16 >> 2, p = b16 & 3;
                int ro = 2 * p + u;
                if (f == 0) {
                    if (e < 4)       val = Wih2[ro * 40 + 4 * e + q];
                    else if (e == 4) val = Wih2[ro * 40 + 16 + q];
                } else {
                    if (e < 4)       val = Wih2[ro * 40 + 20 + 4 * e + q];
                    else if (e == 4) val = Wih2[ro * 40 + 36 + q];
                    else if (q == 0) {
                        if (e == 5)      val = Whh2[ro * 2 + 0];
                        else if (e == 6) val = Whh2[ro * 2 + 1];
                        else             val = bih2[ro] + bhh2[ro];
                    }
                }
            }
            v[e] = val * LOG2E;
        }
        f32x4 lo = {v[0], v[1], v[2], v[3]}, hi4 = {v[4], v[5], v[6], v[7]};
        a2f[f] = pack8v(lo, hi4);
    }

    // ---- init state (all registers) ----
    const float* murow = mu + (size_t)gb * LL;
    float samp0 = eps0[gb] * ex2(0.5f * LOG2E * log_var[(size_t)gb * LL]) + murow[0];

    const f32x4 kz = {0.f, 0.f, 0.f, 0.f};
    f32x2 c01 = {0.f, 0.f}, c23 = {0.f, 0.f};
    float c4 = 0.f, c2 = 0.f;
    float h2self = 0.f, h2oth = 0.f;
    const float* epsp = eps + gb;

    bf16x8 b1;       // L1 B-frag for the next step
    f32x4 g2s;       // deferred L2 pre-activations (previous step)
    float epsv;      // eps of the previous step

    // ---- prologue: step t = 0 ----
    {
        float ldmu = 0.f, ldeps = 0.f;
        if (q == 0) { ldmu = murow[0]; ldeps = *epsp; }
        epsp += BB;

        f32x4 zlo = {0.f, 0.f, 0.f, 0.f};
        f32x4 phi = {0.f, (q == 0) ? samp0 : 0.f, 0.f, 1.f};
        bf16x8 b1p = pack8v(zlo, phi);

        f32x4 acc[5];
        #pragma unroll
        for (int T = 0; T < 5; ++T)
            acc[T] = __builtin_amdgcn_mfma_f32_16x16x32_bf16(a1[T], b1p, kz, 0, 0, 0);

        f32x2 h01, h23;
        float h4;
        lstm_unit2(acc[0], acc[1], c01, h01);
        lstm_unit2(acc[2], acc[3], c23, h23);
        lstm_unit(acc[4], c4, h4);

        f32x4 hv = {h01[0], h01[1], h23[0], h23[1]};
        f32x4 cv = {c01[0], c01[1], c23[0], c23[1]};
        f32x4 b1hi = {h4, ldmu, 0.f, 1.f};
        b1 = pack8v(hv, b1hi);

        f32x4 l0 = {lrelu(hv[0]), lrelu(hv[1]), lrelu(hv[2]), lrelu(hv[3])};
        f32x4 l1 = {lrelu(h4), 0.f, 0.f, 0.f};
        f32x4 l2 = {lrelu(cv[0]), lrelu(cv[1]), lrelu(cv[2]), lrelu(cv[3])};
        f32x4 l3 = {lrelu(c4), h2self, h2oth, 1.f};
        g2s = __builtin_amdgcn_mfma_f32_16x16x32_bf16(a2f[0], pack8v(l0, l1), kz, 0, 0, 0);
        g2s = __builtin_amdgcn_mfma_f32_16x16x32_bf16(a2f[1], pack8v(l2, l3), g2s, 0, 0, 0);
        epsv = ldeps;
    }

    #pragma unroll 2
    for (int t = 1; t < LL; ++t) {
        float ldmu = 0.f, ldeps = 0.f;
        if (q == 0) { ldmu = murow[t]; ldeps = *epsp; }
        epsp += BB;

        // ---- L1: 5 MFMAs ----
        f32x4 acc[5];
        #pragma unroll
        for (int T = 0; T < 5; ++T)
            acc[T] = __builtin_amdgcn_mfma_f32_16x16x32_bf16(a1[T], b1, kz, 0, 0, 0);

        // ---- gates: 3 pair-units (T0T1, T2T3, {T4, deferred L2(t-1)}) ----
        f32x2 h01, h23;
        lstm_unit2(acc[0], acc[1], c01, h01);
        lstm_unit2(acc[2], acc[3], c23, h23);
        f32x2 c42 = {c4, c2}, h42;
        lstm_unit2(acc[4], g2s, c42, h42);
        c4 = c42[0];  c2 = c42[1];
        float h4 = h42[0];
        h2self = h42[1];                       // h2(t-1)
        h2oth  = __shfl_xor(h2self, 16);       // q0 <- h2b(t-1)

        // ---- stage out(t-1) ----
        if (q == 0) {
            int s = (t - 1) & 15;
            obw[0][b16][s] = h2self;
            obw[1][b16][s] = h2oth;
            obw[2][b16][s] = fmaf(epsv, ex2(0.5f * LOG2E * h2oth), h2self);
        }

        // ---- build b1(t+1) and L2 B-frags for step t ----
        f32x4 hv = {h01[0], h01[1], h23[0], h23[1]};
        f32x4 cv = {c01[0], c01[1], c23[0], c23[1]};
        f32x4 b1hi = {h4, ldmu, (float)t, 1.f};
        b1 = pack8v(hv, b1hi);

        f32x4 l0 = {lrelu(hv[0]), lrelu(hv[1]), lrelu(hv[2]), lrelu(hv[3])};
        f32x4 l1 = {lrelu(h4), 0.f, 0.f, 0.f};
        f32x4 l2 = {lrelu(cv[0]), lrelu(cv[1]), lrelu(cv[2]), lrelu(cv[3])};
        f32x4 l3 = {lrelu(c4), h2self, h2oth, 1.f};
        g2s = __builtin_amdgcn_mfma_f32_16x16x32_bf16(a2f[0], pack8v(l0, l1), kz, 0, 0, 0);
        g2s = __builtin_amdgcn_mfma_f32_16x16x32_bf16(a2f[1], pack8v(l2, l3), g2s, 0, 0, 0);
        epsv = ldeps;

        // ---- dump a completed 16-step block (uniform branch) ----
        if ((t & 15) == 0) {
            int bk = (t >> 4) - 1;
            int bq = lane >> 2, ch = lane & 3;
            #pragma unroll
            for (int o = 0; o < 3; ++o) {
                f32x4 v = *reinterpret_cast<const f32x4*>(&obw[o][bq][ch * 4]);
                float* dst = out + (size_t)o * BB * LL + (size_t)(gb0 + bq) * LL
                           + bk * 16 + ch * 4;
                *(float4*)dst = make_float4(v[0], v[1], v[2], v[3]);
            }
        }
    }

    // ---- tail: apply L2 gates for t = 127, stage slot 15, dump block 7 ----
    {
        float h2;
        lstm_unit(g2s, c2, h2);
        float h2o = __shfl_xor(h2, 16);
        if (q == 0) {
            obw[0][b16][15] = h2;
            obw[1][b16][15] = h2o;
            obw[2][b16][15] = fmaf(epsv, ex2(0.5f * LOG2E * h2o), h2);
        }
        int bq = lane >> 2, ch = lane & 3;
        #pragma unroll
        for (int o = 0; o < 3; ++o) {
            f32x4 v = *reinterpret_cast<const f32x4*>(&obw[o][bq][ch * 4]);
            float* dst = out + (size_t)o * BB * LL + (size_t)(gb0 + bq) * LL
                       + 7 * 16 + ch * 4;
            *(float4*)dst = make_float4(v[0], v[1], v[2], v[3]);
        }
    }
}

extern "C" void kernel_launch(void* const* d_in, const int* in_sizes, int n_in,
                              void* d_out, int out_size, void* d_ws, size_t ws_size,
                              hipStream_t stream) {
    sampler_lstm<<<dim3(BB / 64), dim3(256), 0, stream>>>(
        (const float*)d_in[0],  (const float*)d_in[1],  (const float*)d_in[2],
        (const float*)d_in[3],  (const float*)d_in[4],  (const float*)d_in[5],
        (const float*)d_in[6],  (const float*)d_in[7],  (const float*)d_in[8],
        (const float*)d_in[9],  (const float*)d_in[10], (const float*)d_in[11],
        (float*)d_out);
}